// Round 2
// baseline (5760.934 us; speedup 1.0000x reference)
//
#include <hip/hip_runtime.h>
#include <hip/hip_bf16.h>

#define NOER 100000
#define NCON 20000
#define NCLS 1000
#define FENT 64
#define HID 128
#define ESR 200000
#define EEP 400000
#define ECOV 400000
#define EBEL 100000
#define NEG 0.2f

// packed logit/denom offsets (by relation)
#define SL0 0
#define SL1 NOER
#define SL2 (2*NOER)
#define SL3 (2*NOER + NCON)
#define SL4 (2*NOER + 2*NCON)
#define SL_TOT (2*NOER + 2*NCON + NCLS)
#define DL0 0
#define DL1 NOER
#define DL2 (NOER + NCON)
#define DL3 (NOER + NCON + NCLS)
#define DL4 (2*NOER + NCON + NCLS)
#define DL_TOT (2*NOER + 2*NCON + NCLS)
// packed ex offsets
#define EX0 0
#define EX1 500000
#define EX2 900000
#define EX3 1000000
#define EX4 1400000
#define EX_TOT 1500000

__device__ __forceinline__ void atomAdd(float* p, float v) { unsafeAtomicAdd(p, v); }

__device__ __forceinline__ float wredsum(float p) {
#pragma unroll
    for (int off = 32; off; off >>= 1) p += __shfl_down(p, off);
    return p;
}

// out[n, 0:128] = x[n, 0:K] @ W[K,128] (+ bias); BM=64 rows/block, 256 thr, 4x8 per-thread tile
template <int K, bool BIAS>
__global__ __launch_bounds__(256) void k_gemm(const float* __restrict__ x,
                                              const float* __restrict__ W,
                                              const float* __restrict__ bias,
                                              float* __restrict__ out, int n) {
    __shared__ float xs[64][33];   // padded: broadcast scalar reads
    __shared__ float ws[32][128];  // linear: float4 reads, 2-way max
    const int tid = threadIdx.x;
    const int tx = tid & 15;   // col group: cols {4tx..4tx+3} and {64+4tx..}
    const int ty = tid >> 4;   // row group: rows {4ty..4ty+3}
    const int row0 = blockIdx.x * 64;
    float acc[4][8] = {};
    for (int k0 = 0; k0 < K; k0 += 32) {
        __syncthreads();
#pragma unroll
        for (int p = 0; p < 2; ++p) {  // stage x tile 64x32
            int m = tid + p * 256;
            int r = m >> 3, kq = (m & 7) * 4;
            int gr = row0 + r;
            float4 v = make_float4(0.f, 0.f, 0.f, 0.f);
            if (gr < n) v = *(const float4*)(x + (size_t)gr * K + k0 + kq);
            xs[r][kq] = v.x; xs[r][kq + 1] = v.y; xs[r][kq + 2] = v.z; xs[r][kq + 3] = v.w;
        }
#pragma unroll
        for (int p = 0; p < 4; ++p) {  // stage W tile 32x128
            int m = tid + p * 256;
            int r = m >> 5, c4 = (m & 31) * 4;
            *(float4*)(&ws[r][c4]) = *(const float4*)(W + (size_t)(k0 + r) * HID + c4);
        }
        __syncthreads();
#pragma unroll
        for (int k = 0; k < 32; ++k) {
            float xv[4];
#pragma unroll
            for (int i = 0; i < 4; ++i) xv[i] = xs[ty * 4 + i][k];
            float4 w0 = *(const float4*)(&ws[k][tx * 4]);
            float4 w1 = *(const float4*)(&ws[k][64 + tx * 4]);
            float wv[8] = {w0.x, w0.y, w0.z, w0.w, w1.x, w1.y, w1.z, w1.w};
#pragma unroll
            for (int i = 0; i < 4; ++i)
#pragma unroll
                for (int j = 0; j < 8; ++j) acc[i][j] = fmaf(xv[i], wv[j], acc[i][j]);
        }
    }
#pragma unroll
    for (int i = 0; i < 4; ++i) {
        int gr = row0 + ty * 4 + i;
        if (gr >= n) continue;
        float4 o0, o1;
        o0.x = acc[i][0]; o0.y = acc[i][1]; o0.z = acc[i][2]; o0.w = acc[i][3];
        o1.x = acc[i][4]; o1.y = acc[i][5]; o1.z = acc[i][6]; o1.w = acc[i][7];
        if (BIAS) {
            const float4 b0 = *(const float4*)(bias + tx * 4);
            const float4 b1 = *(const float4*)(bias + 64 + tx * 4);
            o0.x += b0.x; o0.y += b0.y; o0.z += b0.z; o0.w += b0.w;
            o1.x += b1.x; o1.y += b1.y; o1.z += b1.z; o1.w += b1.w;
        }
        *(float4*)(out + (size_t)gr * HID + tx * 4) = o0;
        *(float4*)(out + (size_t)gr * HID + 64 + tx * 4) = o1;
    }
}

// all 20 attention projection vectors: wsv[a] = Wsrc[a] @ att_src[a], wdv[a] = Wdst[a] @ att_dst[a]
__global__ void k_wvec(const float* __restrict__ Wsrc, const float* __restrict__ as_,
                       const float* __restrict__ Wdst, const float* __restrict__ ad,
                       float* __restrict__ wsv, float* __restrict__ wdv) {
    int a = blockIdx.x >> 5;
    int r = ((blockIdx.x & 31) << 2) + (threadIdx.x >> 6);
    int lane = threadIdx.x & 63;
    const float *W, *v;
    float* o;
    if (a < 10) { W = Wsrc + (size_t)a * HID * HID; v = as_ + a * HID; o = wsv + a * HID; }
    else { W = Wdst + (size_t)(a - 10) * HID * HID; v = ad + (a - 10) * HID; o = wdv + (a - 10) * HID; }
    float p = W[r * HID + lane] * v[lane] + W[r * HID + 64 + lane] * v[64 + lane];
    p = wredsum(p);
    if (lane == 0) o[r] = p;
}

// up to 4 dots per node over x[n,128]; one wave per node
__global__ void k_dots(const float* __restrict__ x, int n,
                       const float* __restrict__ v0, float* __restrict__ o0,
                       const float* __restrict__ v1, float* __restrict__ o1,
                       const float* __restrict__ v2, float* __restrict__ o2,
                       const float* __restrict__ v3, float* __restrict__ o3) {
    int t = blockIdx.x * blockDim.x + threadIdx.x;
    int node = t >> 6, lane = t & 63;
    if (node >= n) return;
    float x0 = x[(size_t)node * HID + lane], x1 = x[(size_t)node * HID + 64 + lane];
    float p0 = v0 ? x0 * v0[lane] + x1 * v0[64 + lane] : 0.f;
    float p1 = v1 ? x0 * v1[lane] + x1 * v1[64 + lane] : 0.f;
    float p2 = v2 ? x0 * v2[lane] + x1 * v2[64 + lane] : 0.f;
    float p3 = v3 ? x0 * v3[lane] + x1 * v3[64 + lane] : 0.f;
    p0 = wredsum(p0); p1 = wredsum(p1); p2 = wredsum(p2); p3 = wredsum(p3);
    if (lane == 0) {
        if (o0) o0[node] = p0;
        if (o1) o1[node] = p1;
        if (o2) o2[node] = p2;
        if (o3) o3[node] = p3;
    }
}

// batched over all 5 relations: ex[e] = exp(leaky_relu(sl+dl)); denom += ex
__global__ void k_edge_all(const int* __restrict__ ep, const int* __restrict__ cov,
                           const int* __restrict__ bel, const int* __restrict__ rcov,
                           const int* __restrict__ rbel,
                           const float* __restrict__ sl, const float* __restrict__ dl,
                           float* __restrict__ ex, float* __restrict__ denom) {
    int e = blockIdx.x * blockDim.x + threadIdx.x;
    if (e >= EX_TOT) return;
    int s, d, slo, dlo;
    if (e < EX1) {
        slo = SL0; dlo = DL0;
        if (e < EEP) { s = ep[e]; d = ep[EEP + e]; } else { s = e - EEP; d = s; }
    } else if (e < EX2) { int i = e - EX1; s = cov[i];  d = cov[ECOV + i];  slo = SL1; dlo = DL1; }
    else if (e < EX3)   { int i = e - EX2; s = bel[i];  d = bel[EBEL + i];  slo = SL2; dlo = DL2; }
    else if (e < EX4)   { int i = e - EX3; s = rcov[i]; d = rcov[ECOV + i]; slo = SL3; dlo = DL3; }
    else                { int i = e - EX4; s = rbel[i]; d = rbel[EBEL + i]; slo = SL4; dlo = DL4; }
    float lg = sl[slo + s] + dl[dlo + d];
    lg = lg > 0.f ? lg : NEG * lg;
    float v = expf(lg);
    ex[e] = v;
    atomAdd(denom + dlo + d, v);
}

// 32 threads per edge, float4 channels: acc[d,:] += (ex/denom[d]) * hs[s,:]
__global__ void k_scatter_v4(const int* __restrict__ src, const int* __restrict__ dst,
                             int ne, int nloop,
                             const float* __restrict__ ex, const float* __restrict__ denom,
                             const float* __restrict__ hs, float* __restrict__ acc) {
    int e = blockIdx.x * 8 + (threadIdx.x >> 5);
    if (e >= ne + nloop) return;
    int c = (threadIdx.x & 31) * 4;
    int s, d;
    if (e < ne) { s = src[e]; d = dst[e]; } else { s = e - ne; d = s; }
    float a = ex[e] / denom[d];
    const float4 hv = *(const float4*)(hs + (size_t)s * HID + c);
    float* ap = acc + (size_t)d * HID + c;
    atomAdd(ap, a * hv.x); atomAdd(ap + 1, a * hv.y);
    atomAdd(ap + 2, a * hv.z); atomAdd(ap + 3, a * hv.w);
}

__global__ void k_merge2(const float* __restrict__ acc, const float* __restrict__ bA,
                         const float* __restrict__ bB, float* __restrict__ h, int n) {
    int i = blockIdx.x * blockDim.x + threadIdx.x;
    if (i >= n) return;
    int c = i & (HID - 1);
    h[i] = 0.5f * (acc[i] + bA[c] + bB[c]);
}

__global__ void k_merge1(const float* __restrict__ acc, const float* __restrict__ b,
                         float* __restrict__ h, int n) {
    int i = blockIdx.x * blockDim.x + threadIdx.x;
    if (i >= n) return;
    h[i] = acc[i] + b[i & (HID - 1)];
}

__global__ void k_score(const float* __restrict__ x, const float* __restrict__ h,
                        const float* __restrict__ Wc, float* __restrict__ s1,
                        float* __restrict__ s2, int n_nodes) {
    int t = blockIdx.x * blockDim.x + threadIdx.x;
    int n = t >> 6, lane = t & 63;
    if (n >= n_nodes) return;
    float xv = x[(size_t)n * FENT + lane];
    float h0 = h[(size_t)n * HID + lane], h1 = h[(size_t)n * HID + 64 + lane];
    float p1 = xv * Wc[lane] + h0 * Wc[64 + lane] + h1 * Wc[128 + lane];
    float p2 = xv * Wc[192 + lane] + h0 * Wc[256 + lane] + h1 * Wc[320 + lane];
#pragma unroll
    for (int off = 32; off; off >>= 1) { p1 += __shfl_down(p1, off); p2 += __shfl_down(p2, off); }
    if (lane == 0) { s1[n] = p1; s2[n] = p2; }
}

__global__ void k_final(const int* __restrict__ src, const int* __restrict__ dst,
                        const float* __restrict__ s1, const float* __restrict__ s2,
                        const float* __restrict__ bcls, float* __restrict__ out) {
    int e = blockIdx.x * blockDim.x + threadIdx.x;
    if (e >= ESR) return;
    out[e] = s1[src[e]] + s2[dst[e]] + bcls[0];
}

extern "C" void kernel_launch(void* const* d_in, const int* in_sizes, int n_in,
                              void* d_out, int out_size, void* d_ws, size_t ws_size,
                              hipStream_t stream) {
    const float* x_oer   = (const float*)d_in[0];
    const float* e_oer   = (const float*)d_in[3];
    const float* e_con   = (const float*)d_in[4];
    const float* e_cls   = (const float*)d_in[5];
    const float* W_lin   = (const float*)d_in[6];
    const float* b_lin   = (const float*)d_in[7];
    const float* Wsrc    = (const float*)d_in[8];
    const float* Wdst    = (const float*)d_in[9];
    const float* att_src = (const float*)d_in[10];
    const float* att_dst = (const float*)d_in[11];
    const float* b_gat   = (const float*)d_in[12];
    const float* W_cls   = (const float*)d_in[13];
    const float* b_cls   = (const float*)d_in[14];
    const int* ei_sr   = (const int*)d_in[15];
    const int* ei_cov  = (const int*)d_in[16];
    const int* ei_bel  = (const int*)d_in[17];
    const int* ei_rcov = (const int*)d_in[18];
    const int* ei_rbel = (const int*)d_in[19];
    const int* ei_ep   = (const int*)d_in[20];

    float* ws = (float*)d_ws;
    size_t o = 0;
    float* h_oer   = ws + o; o += (size_t)NOER * HID;
    float* h_con   = ws + o; o += (size_t)NCON * HID;
    float* h_cls   = ws + o; o += (size_t)NCLS * HID;
    float* acc_oer = ws + o; o += (size_t)NOER * HID;
    float* acc_con = ws + o; o += (size_t)NCON * HID;
    float* acc_cls = ws + o; o += (size_t)NCLS * HID;
    float* hs      = ws + o; o += (size_t)NOER * HID;
    float* slp     = ws + o; o += SL_TOT;
    float* dlp     = ws + o; o += DL_TOT;
    float* denom   = ws + o; o += DL_TOT;
    float* ex      = ws + o; o += EX_TOT;
    float* wsv     = ws + o; o += 10 * HID;
    float* wdv     = ws + o; o += 10 * HID;
    float* s1      = ws + o; o += NOER;
    float* s2      = ws + o; o += NOER;

    k_wvec<<<640, 256, 0, stream>>>(Wsrc, att_src, Wdst, att_dst, wsv, wdv);

    k_gemm<FENT, true><<<(NOER + 63) / 64, 256, 0, stream>>>(e_oer, W_lin + 0 * FENT * HID, b_lin + 0 * HID, h_oer, NOER);
    k_gemm<FENT, true><<<(NCON + 63) / 64, 256, 0, stream>>>(e_con, W_lin + 1 * FENT * HID, b_lin + 1 * HID, h_con, NCON);
    k_gemm<FENT, true><<<(NCLS + 63) / 64, 256, 0, stream>>>(e_cls, W_lin + 2 * FENT * HID, b_lin + 2 * HID, h_cls, NCLS);

    for (int l = 0; l < 2; ++l) {
        int b = l * 5;
        // logit GEMVs, batched per node type
        k_dots<<<(NOER * 64 + 255) / 256, 256, 0, stream>>>(h_oer, NOER,
            wsv + (b + 0) * HID, slp + SL0, wdv + (b + 0) * HID, dlp + DL0,
            wsv + (b + 1) * HID, slp + SL1, wdv + (b + 3) * HID, dlp + DL3);
        k_dots<<<(NCON * 64 + 255) / 256, 256, 0, stream>>>(h_con, NCON,
            wsv + (b + 2) * HID, slp + SL2, wsv + (b + 3) * HID, slp + SL3,
            wdv + (b + 1) * HID, dlp + DL1, wdv + (b + 4) * HID, dlp + DL4);
        k_dots<<<(NCLS * 64 + 255) / 256, 256, 0, stream>>>(h_cls, NCLS,
            wsv + (b + 4) * HID, slp + SL4, wdv + (b + 2) * HID, dlp + DL2,
            nullptr, nullptr, nullptr, nullptr);
        hipMemsetAsync(denom, 0, DL_TOT * sizeof(float), stream);
        hipMemsetAsync(acc_oer, 0, ((size_t)NOER + NCON + NCLS) * HID * sizeof(float), stream);
        k_edge_all<<<(EX_TOT + 255) / 256, 256, 0, stream>>>(ei_ep, ei_cov, ei_bel, ei_rcov, ei_rbel,
                                                             slp, dlp, ex, denom);
        // r0: oer->oer (ep, with self loops)
        k_gemm<HID, false><<<(NOER + 63) / 64, 256, 0, stream>>>(h_oer, Wsrc + (size_t)(b + 0) * HID * HID, nullptr, hs, NOER);
        k_scatter_v4<<<(EEP + NOER + 7) / 8, 256, 0, stream>>>(ei_ep, ei_ep + EEP, EEP, NOER,
                                                               ex + EX0, denom + DL0, hs, acc_oer);
        // r1: oer->con (covers)
        k_gemm<HID, false><<<(NOER + 63) / 64, 256, 0, stream>>>(h_oer, Wsrc + (size_t)(b + 1) * HID * HID, nullptr, hs, NOER);
        k_scatter_v4<<<(ECOV + 7) / 8, 256, 0, stream>>>(ei_cov, ei_cov + ECOV, ECOV, 0,
                                                         ex + EX1, denom + DL1, hs, acc_con);
        // r2: con->cls (belongs)
        k_gemm<HID, false><<<(NCON + 63) / 64, 256, 0, stream>>>(h_con, Wsrc + (size_t)(b + 2) * HID * HID, nullptr, hs, NCON);
        k_scatter_v4<<<(EBEL + 7) / 8, 256, 0, stream>>>(ei_bel, ei_bel + EBEL, EBEL, 0,
                                                         ex + EX2, denom + DL2, hs, acc_cls);
        // r3: con->oer (rev covers)
        k_gemm<HID, false><<<(NCON + 63) / 64, 256, 0, stream>>>(h_con, Wsrc + (size_t)(b + 3) * HID * HID, nullptr, hs, NCON);
        k_scatter_v4<<<(ECOV + 7) / 8, 256, 0, stream>>>(ei_rcov, ei_rcov + ECOV, ECOV, 0,
                                                         ex + EX3, denom + DL3, hs, acc_oer);
        // r4: cls->con (rev belongs)
        k_gemm<HID, false><<<(NCLS + 63) / 64, 256, 0, stream>>>(h_cls, Wsrc + (size_t)(b + 4) * HID * HID, nullptr, hs, NCLS);
        k_scatter_v4<<<(EBEL + 7) / 8, 256, 0, stream>>>(ei_rbel, ei_rbel + EBEL, EBEL, 0,
                                                         ex + EX4, denom + DL4, hs, acc_con);

        k_merge2<<<(NOER * HID + 255) / 256, 256, 0, stream>>>(acc_oer, b_gat + (b + 0) * HID,
                                                               b_gat + (b + 3) * HID, h_oer, NOER * HID);
        k_merge2<<<(NCON * HID + 255) / 256, 256, 0, stream>>>(acc_con, b_gat + (b + 1) * HID,
                                                               b_gat + (b + 4) * HID, h_con, NCON * HID);
        k_merge1<<<(NCLS * HID + 255) / 256, 256, 0, stream>>>(acc_cls, b_gat + (b + 2) * HID,
                                                               h_cls, NCLS * HID);
    }

    k_score<<<(NOER * 64 + 255) / 256, 256, 0, stream>>>(x_oer, h_oer, W_cls, s1, s2, NOER);
    k_final<<<(ESR + 255) / 256, 256, 0, stream>>>(ei_sr, ei_sr + ESR, s1, s2, b_cls, (float*)d_out);
}

// Round 3
// 1162.362 us; speedup vs baseline: 4.9562x; 4.9562x over previous
//
#include <hip/hip_runtime.h>
#include <hip/hip_bf16.h>

#define NOER 100000
#define NCON 20000
#define NCLS 1000
#define FENT 64
#define HID 128
#define ESR 200000
#define EEP 400000
#define ECOV 400000
#define EBEL 100000
#define NEG 0.2f

// packed src-logit offsets (by relation)
#define SL0 0
#define SL1 NOER
#define SL2 (2*NOER)
#define SL3 (2*NOER + NCON)
#define SL4 (2*NOER + 2*NCON)
#define SL_TOT (2*NOER + 2*NCON + NCLS)
// packed dst offsets (dst-logit / CSR segment space)
#define DL0 0
#define DL1 NOER
#define DL2 (NOER + NCON)
#define DL3 (NOER + NCON + NCLS)
#define DL4 (2*NOER + NCON + NCLS)
#define DL_TOT (2*NOER + 2*NCON + NCLS)   // 241000
// packed edge offsets (global edge id -> relation)
#define EX0 0
#define EX1 500000
#define EX2 900000
#define EX3 1000000
#define EX4 1400000
#define EX_TOT 1500000

#define SCAN_B1 ((DL_TOT + 255) / 256)    // 942 blocks

__device__ __forceinline__ float wredsum(float p) {
#pragma unroll
    for (int off = 32; off; off >>= 1) p += __shfl_down(p, off);
    return p;
}

// decode global edge id -> (src within relation, global packed dst index)
__device__ __forceinline__ void edge_decode(int e, const int* __restrict__ ep,
                                            const int* __restrict__ cov,
                                            const int* __restrict__ bel,
                                            const int* __restrict__ rcov,
                                            const int* __restrict__ rbel,
                                            int& s, int& g) {
    if (e < EX1) {
        if (e < EEP) { s = ep[e]; g = DL0 + ep[EEP + e]; }
        else { s = e - EEP; g = DL0 + s; }               // self loops
    } else if (e < EX2) { int i = e - EX1; s = cov[i];  g = DL1 + cov[ECOV + i]; }
    else if (e < EX3)   { int i = e - EX2; s = bel[i];  g = DL2 + bel[EBEL + i]; }
    else if (e < EX4)   { int i = e - EX3; s = rcov[i]; g = DL3 + rcov[ECOV + i]; }
    else                { int i = e - EX4; s = rbel[i]; g = DL4 + rbel[EBEL + i]; }
}

// ---------------- CSR build ----------------
__global__ void k_count(const int* __restrict__ ep, const int* __restrict__ cov,
                        const int* __restrict__ bel, const int* __restrict__ rcov,
                        const int* __restrict__ rbel, int* __restrict__ counts) {
    int e = blockIdx.x * blockDim.x + threadIdx.x;
    if (e >= EX_TOT) return;
    int s, g;
    edge_decode(e, ep, cov, bel, rcov, rbel, s, g);
    atomicAdd(counts + g, 1);
}

// block-level inclusive scan (256), partials + block sums
__global__ void k_scan1(const int* __restrict__ counts, int* __restrict__ part,
                        int* __restrict__ bsum) {
    __shared__ int sm[256];
    int i = blockIdx.x * 256 + threadIdx.x;
    int v = (i < DL_TOT) ? counts[i] : 0;
    sm[threadIdx.x] = v;
    __syncthreads();
#pragma unroll
    for (int off = 1; off < 256; off <<= 1) {
        int x = (threadIdx.x >= off) ? sm[threadIdx.x - off] : 0;
        __syncthreads();
        sm[threadIdx.x] += x;
        __syncthreads();
    }
    if (i < DL_TOT) part[i] = sm[threadIdx.x];
    if (threadIdx.x == 255) bsum[blockIdx.x] = sm[255];
}

// single-block inclusive scan of block sums (SCAN_B1 <= 1024)
__global__ void k_scan2(int* __restrict__ bsum) {
    __shared__ int sm[1024];
    int t = threadIdx.x;
    sm[t] = (t < SCAN_B1) ? bsum[t] : 0;
    __syncthreads();
#pragma unroll
    for (int off = 1; off < 1024; off <<= 1) {
        int x = (t >= off) ? sm[t - off] : 0;
        __syncthreads();
        sm[t] += x;
        __syncthreads();
    }
    if (t < SCAN_B1) bsum[t] = sm[t];
}

// final inclusive scan S and cursor (= exclusive scan)
__global__ void k_scan3(const int* __restrict__ part, const int* __restrict__ bsum,
                        const int* __restrict__ counts, int* __restrict__ S,
                        int* __restrict__ cursor) {
    int i = blockIdx.x * 256 + threadIdx.x;
    if (i >= DL_TOT) return;
    int b = blockIdx.x;
    int s = part[i] + (b > 0 ? bsum[b - 1] : 0);
    S[i] = s;
    cursor[i] = s - counts[i];
}

__global__ void k_fill(const int* __restrict__ ep, const int* __restrict__ cov,
                       const int* __restrict__ bel, const int* __restrict__ rcov,
                       const int* __restrict__ rbel, int* __restrict__ cursor,
                       int* __restrict__ csr) {
    int e = blockIdx.x * blockDim.x + threadIdx.x;
    if (e >= EX_TOT) return;
    int s, g;
    edge_decode(e, ep, cov, bel, rcov, rbel, s, g);
    int pos = atomicAdd(cursor + g, 1);
    csr[pos] = s;
}

// ---------------- dense math ----------------
// out[n, 0:128] = x[n, 0:K] @ W[K,128] (+ bias); BM=64 rows/block, 256 thr, 4x8 tile
template <int K, bool BIAS>
__global__ __launch_bounds__(256) void k_gemm(const float* __restrict__ x,
                                              const float* __restrict__ W,
                                              const float* __restrict__ bias,
                                              float* __restrict__ out, int n) {
    __shared__ float xs[64][33];
    __shared__ float ws[32][128];
    const int tid = threadIdx.x;
    const int tx = tid & 15;
    const int ty = tid >> 4;
    const int row0 = blockIdx.x * 64;
    float acc[4][8] = {};
    for (int k0 = 0; k0 < K; k0 += 32) {
        __syncthreads();
#pragma unroll
        for (int p = 0; p < 2; ++p) {
            int m = tid + p * 256;
            int r = m >> 3, kq = (m & 7) * 4;
            int gr = row0 + r;
            float4 v = make_float4(0.f, 0.f, 0.f, 0.f);
            if (gr < n) v = *(const float4*)(x + (size_t)gr * K + k0 + kq);
            xs[r][kq] = v.x; xs[r][kq + 1] = v.y; xs[r][kq + 2] = v.z; xs[r][kq + 3] = v.w;
        }
#pragma unroll
        for (int p = 0; p < 4; ++p) {
            int m = tid + p * 256;
            int r = m >> 5, c4 = (m & 31) * 4;
            *(float4*)(&ws[r][c4]) = *(const float4*)(W + (size_t)(k0 + r) * HID + c4);
        }
        __syncthreads();
#pragma unroll
        for (int k = 0; k < 32; ++k) {
            float xv[4];
#pragma unroll
            for (int i = 0; i < 4; ++i) xv[i] = xs[ty * 4 + i][k];
            float4 w0 = *(const float4*)(&ws[k][tx * 4]);
            float4 w1 = *(const float4*)(&ws[k][64 + tx * 4]);
            float wv[8] = {w0.x, w0.y, w0.z, w0.w, w1.x, w1.y, w1.z, w1.w};
#pragma unroll
            for (int i = 0; i < 4; ++i)
#pragma unroll
                for (int j = 0; j < 8; ++j) acc[i][j] = fmaf(xv[i], wv[j], acc[i][j]);
        }
    }
#pragma unroll
    for (int i = 0; i < 4; ++i) {
        int gr = row0 + ty * 4 + i;
        if (gr >= n) continue;
        float4 o0, o1;
        o0.x = acc[i][0]; o0.y = acc[i][1]; o0.z = acc[i][2]; o0.w = acc[i][3];
        o1.x = acc[i][4]; o1.y = acc[i][5]; o1.z = acc[i][6]; o1.w = acc[i][7];
        if (BIAS) {
            const float4 b0 = *(const float4*)(bias + tx * 4);
            const float4 b1 = *(const float4*)(bias + 64 + tx * 4);
            o0.x += b0.x; o0.y += b0.y; o0.z += b0.z; o0.w += b0.w;
            o1.x += b1.x; o1.y += b1.y; o1.z += b1.z; o1.w += b1.w;
        }
        *(float4*)(out + (size_t)gr * HID + tx * 4) = o0;
        *(float4*)(out + (size_t)gr * HID + 64 + tx * 4) = o1;
    }
}

// all 20 attention projection vectors
__global__ void k_wvec(const float* __restrict__ Wsrc, const float* __restrict__ as_,
                       const float* __restrict__ Wdst, const float* __restrict__ ad,
                       float* __restrict__ wsv, float* __restrict__ wdv) {
    int a = blockIdx.x >> 5;
    int r = ((blockIdx.x & 31) << 2) + (threadIdx.x >> 6);
    int lane = threadIdx.x & 63;
    const float *W, *v;
    float* o;
    if (a < 10) { W = Wsrc + (size_t)a * HID * HID; v = as_ + a * HID; o = wsv + a * HID; }
    else { W = Wdst + (size_t)(a - 10) * HID * HID; v = ad + (a - 10) * HID; o = wdv + (a - 10) * HID; }
    float p = W[r * HID + lane] * v[lane] + W[r * HID + 64 + lane] * v[64 + lane];
    p = wredsum(p);
    if (lane == 0) o[r] = p;
}

// up to 4 dots per node over x[n,128]; one wave per node
__global__ void k_dots(const float* __restrict__ x, int n,
                       const float* __restrict__ v0, float* __restrict__ o0,
                       const float* __restrict__ v1, float* __restrict__ o1,
                       const float* __restrict__ v2, float* __restrict__ o2,
                       const float* __restrict__ v3, float* __restrict__ o3) {
    int t = blockIdx.x * blockDim.x + threadIdx.x;
    int node = t >> 6, lane = t & 63;
    if (node >= n) return;
    float x0 = x[(size_t)node * HID + lane], x1 = x[(size_t)node * HID + 64 + lane];
    float p0 = v0 ? x0 * v0[lane] + x1 * v0[64 + lane] : 0.f;
    float p1 = v1 ? x0 * v1[lane] + x1 * v1[64 + lane] : 0.f;
    float p2 = v2 ? x0 * v2[lane] + x1 * v2[64 + lane] : 0.f;
    float p3 = v3 ? x0 * v3[lane] + x1 * v3[64 + lane] : 0.f;
    p0 = wredsum(p0); p1 = wredsum(p1); p2 = wredsum(p2); p3 = wredsum(p3);
    if (lane == 0) {
        if (o0) o0[node] = p0;
        if (o1) o1[node] = p1;
        if (o2) o2[node] = p2;
        if (o3) o3[node] = p3;
    }
}

// ---------------- atomic-free GAT aggregation ----------------
// one wave per dst node; acc = sum_e ex_e * hs[src_e,:], denom = sum ex; out = acc/denom
template <bool ADD>
__global__ __launch_bounds__(256) void k_agg(const int* __restrict__ csr,
                                             const int* __restrict__ S, int g0,
                                             const float* __restrict__ sl,
                                             const float* __restrict__ dl,
                                             const float* __restrict__ hs,
                                             float* __restrict__ out, int n_dst) {
    int d = blockIdx.x * 4 + (threadIdx.x >> 6);
    if (d >= n_dst) return;
    int lane = threadIdx.x & 63;
    int g = g0 + d;
    int beg = (g == 0) ? 0 : S[g - 1];
    int end = S[g];
    float dld = dl[d];
    float a0 = 0.f, a1 = 0.f, den = 0.f;
    for (int i = beg; i < end; ++i) {
        int s = csr[i];
        float lg = sl[s] + dld;
        lg = lg > 0.f ? lg : NEG * lg;
        float ex = expf(lg);
        den += ex;
        a0 = fmaf(ex, hs[(size_t)s * HID + lane], a0);
        a1 = fmaf(ex, hs[(size_t)s * HID + 64 + lane], a1);
    }
    float inv = (end > beg) ? 1.f / den : 0.f;
    float r0 = a0 * inv, r1 = a1 * inv;
    float* p = out + (size_t)d * HID;
    if (ADD) { p[lane] += r0; p[64 + lane] += r1; }
    else { p[lane] = r0; p[64 + lane] = r1; }
}

__global__ void k_merge2(const float* __restrict__ acc, const float* __restrict__ bA,
                         const float* __restrict__ bB, float* __restrict__ h, int n) {
    int i = blockIdx.x * blockDim.x + threadIdx.x;
    if (i >= n) return;
    int c = i & (HID - 1);
    h[i] = 0.5f * (acc[i] + bA[c] + bB[c]);
}

__global__ void k_merge1(const float* __restrict__ acc, const float* __restrict__ b,
                         float* __restrict__ h, int n) {
    int i = blockIdx.x * blockDim.x + threadIdx.x;
    if (i >= n) return;
    h[i] = acc[i] + b[i & (HID - 1)];
}

__global__ void k_score(const float* __restrict__ x, const float* __restrict__ h,
                        const float* __restrict__ Wc, float* __restrict__ s1,
                        float* __restrict__ s2, int n_nodes) {
    int t = blockIdx.x * blockDim.x + threadIdx.x;
    int n = t >> 6, lane = t & 63;
    if (n >= n_nodes) return;
    float xv = x[(size_t)n * FENT + lane];
    float h0 = h[(size_t)n * HID + lane], h1 = h[(size_t)n * HID + 64 + lane];
    float p1 = xv * Wc[lane] + h0 * Wc[64 + lane] + h1 * Wc[128 + lane];
    float p2 = xv * Wc[192 + lane] + h0 * Wc[256 + lane] + h1 * Wc[320 + lane];
#pragma unroll
    for (int off = 32; off; off >>= 1) { p1 += __shfl_down(p1, off); p2 += __shfl_down(p2, off); }
    if (lane == 0) { s1[n] = p1; s2[n] = p2; }
}

__global__ void k_final(const int* __restrict__ src, const int* __restrict__ dst,
                        const float* __restrict__ s1, const float* __restrict__ s2,
                        const float* __restrict__ bcls, float* __restrict__ out) {
    int e = blockIdx.x * blockDim.x + threadIdx.x;
    if (e >= ESR) return;
    out[e] = s1[src[e]] + s2[dst[e]] + bcls[0];
}

extern "C" void kernel_launch(void* const* d_in, const int* in_sizes, int n_in,
                              void* d_out, int out_size, void* d_ws, size_t ws_size,
                              hipStream_t stream) {
    const float* x_oer   = (const float*)d_in[0];
    const float* e_oer   = (const float*)d_in[3];
    const float* e_con   = (const float*)d_in[4];
    const float* e_cls   = (const float*)d_in[5];
    const float* W_lin   = (const float*)d_in[6];
    const float* b_lin   = (const float*)d_in[7];
    const float* Wsrc    = (const float*)d_in[8];
    const float* Wdst    = (const float*)d_in[9];
    const float* att_src = (const float*)d_in[10];
    const float* att_dst = (const float*)d_in[11];
    const float* b_gat   = (const float*)d_in[12];
    const float* W_cls   = (const float*)d_in[13];
    const float* b_cls   = (const float*)d_in[14];
    const int* ei_sr   = (const int*)d_in[15];
    const int* ei_cov  = (const int*)d_in[16];
    const int* ei_bel  = (const int*)d_in[17];
    const int* ei_rcov = (const int*)d_in[18];
    const int* ei_rbel = (const int*)d_in[19];
    const int* ei_ep   = (const int*)d_in[20];

    float* ws = (float*)d_ws;
    size_t o = 0;
    float* h_oer   = ws + o; o += (size_t)NOER * HID;
    float* h_con   = ws + o; o += (size_t)NCON * HID;
    float* h_cls   = ws + o; o += (size_t)NCLS * HID;
    float* acc_oer = ws + o; o += (size_t)NOER * HID;
    float* acc_con = ws + o; o += (size_t)NCON * HID;
    float* acc_cls = ws + o; o += (size_t)NCLS * HID;
    float* hs      = ws + o; o += (size_t)NOER * HID;
    float* slp     = ws + o; o += SL_TOT;
    float* dlp     = ws + o; o += DL_TOT;
    float* wsv     = ws + o; o += 10 * HID;
    float* wdv     = ws + o; o += 10 * HID;
    float* s1      = ws + o; o += NOER;
    float* s2      = ws + o; o += NOER;
    int* counts = (int*)(ws + o); o += DL_TOT;
    int* part   = (int*)(ws + o); o += DL_TOT;
    int* S      = (int*)(ws + o); o += DL_TOT;
    int* cursor = (int*)(ws + o); o += DL_TOT;
    int* bsum   = (int*)(ws + o); o += 1024;
    int* csr    = (int*)(ws + o); o += EX_TOT;

    // ---- CSR build (all 5 relations packed) ----
    hipMemsetAsync(counts, 0, DL_TOT * sizeof(int), stream);
    k_count<<<(EX_TOT + 255) / 256, 256, 0, stream>>>(ei_ep, ei_cov, ei_bel, ei_rcov, ei_rbel, counts);
    k_scan1<<<SCAN_B1, 256, 0, stream>>>(counts, part, bsum);
    k_scan2<<<1, 1024, 0, stream>>>(bsum);
    k_scan3<<<SCAN_B1, 256, 0, stream>>>(part, bsum, counts, S, cursor);
    k_fill<<<(EX_TOT + 255) / 256, 256, 0, stream>>>(ei_ep, ei_cov, ei_bel, ei_rcov, ei_rbel, cursor, csr);

    k_wvec<<<640, 256, 0, stream>>>(Wsrc, att_src, Wdst, att_dst, wsv, wdv);

    // input projections
    k_gemm<FENT, true><<<(NOER + 63) / 64, 256, 0, stream>>>(e_oer, W_lin + 0 * FENT * HID, b_lin + 0 * HID, h_oer, NOER);
    k_gemm<FENT, true><<<(NCON + 63) / 64, 256, 0, stream>>>(e_con, W_lin + 1 * FENT * HID, b_lin + 1 * HID, h_con, NCON);
    k_gemm<FENT, true><<<(NCLS + 63) / 64, 256, 0, stream>>>(e_cls, W_lin + 2 * FENT * HID, b_lin + 2 * HID, h_cls, NCLS);

    for (int l = 0; l < 2; ++l) {
        int b = l * 5;
        // logit GEMVs, batched per node type
        k_dots<<<(NOER * 64 + 255) / 256, 256, 0, stream>>>(h_oer, NOER,
            wsv + (b + 0) * HID, slp + SL0, wdv + (b + 0) * HID, dlp + DL0,
            wsv + (b + 1) * HID, slp + SL1, wdv + (b + 3) * HID, dlp + DL3);
        k_dots<<<(NCON * 64 + 255) / 256, 256, 0, stream>>>(h_con, NCON,
            wsv + (b + 2) * HID, slp + SL2, wsv + (b + 3) * HID, slp + SL3,
            wdv + (b + 1) * HID, dlp + DL1, wdv + (b + 4) * HID, dlp + DL4);
        k_dots<<<(NCLS * 64 + 255) / 256, 256, 0, stream>>>(h_cls, NCLS,
            wsv + (b + 4) * HID, slp + SL4, wdv + (b + 2) * HID, dlp + DL2,
            nullptr, nullptr, nullptr, nullptr);

        // r0: oer->oer (ep + self loops)
        k_gemm<HID, false><<<(NOER + 63) / 64, 256, 0, stream>>>(h_oer, Wsrc + (size_t)(b + 0) * HID * HID, nullptr, hs, NOER);
        k_agg<false><<<(NOER + 3) / 4, 256, 0, stream>>>(csr, S, DL0, slp + SL0, dlp + DL0, hs, acc_oer, NOER);
        // r1: oer->con (covers)
        k_gemm<HID, false><<<(NOER + 63) / 64, 256, 0, stream>>>(h_oer, Wsrc + (size_t)(b + 1) * HID * HID, nullptr, hs, NOER);
        k_agg<false><<<(NCON + 3) / 4, 256, 0, stream>>>(csr, S, DL1, slp + SL1, dlp + DL1, hs, acc_con, NCON);
        // r2: con->cls (belongs)
        k_gemm<HID, false><<<(NCON + 63) / 64, 256, 0, stream>>>(h_con, Wsrc + (size_t)(b + 2) * HID * HID, nullptr, hs, NCON);
        k_agg<false><<<(NCLS + 3) / 4, 256, 0, stream>>>(csr, S, DL2, slp + SL2, dlp + DL2, hs, acc_cls, NCLS);
        // r3: con->oer (rev covers)
        k_gemm<HID, false><<<(NCON + 63) / 64, 256, 0, stream>>>(h_con, Wsrc + (size_t)(b + 3) * HID * HID, nullptr, hs, NCON);
        k_agg<true><<<(NOER + 3) / 4, 256, 0, stream>>>(csr, S, DL3, slp + SL3, dlp + DL3, hs, acc_oer, NOER);
        // r4: cls->con (rev belongs)
        k_gemm<HID, false><<<(NCLS + 63) / 64, 256, 0, stream>>>(h_cls, Wsrc + (size_t)(b + 4) * HID * HID, nullptr, hs, NCLS);
        k_agg<true><<<(NCON + 3) / 4, 256, 0, stream>>>(csr, S, DL4, slp + SL4, dlp + DL4, hs, acc_con, NCON);

        k_merge2<<<(NOER * HID + 255) / 256, 256, 0, stream>>>(acc_oer, b_gat + (b + 0) * HID,
                                                               b_gat + (b + 3) * HID, h_oer, NOER * HID);
        k_merge2<<<(NCON * HID + 255) / 256, 256, 0, stream>>>(acc_con, b_gat + (b + 1) * HID,
                                                               b_gat + (b + 4) * HID, h_con, NCON * HID);
        k_merge1<<<(NCLS * HID + 255) / 256, 256, 0, stream>>>(acc_cls, b_gat + (b + 2) * HID,
                                                               h_cls, NCLS * HID);
    }

    k_score<<<(NOER * 64 + 255) / 256, 256, 0, stream>>>(x_oer, h_oer, W_cls, s1, s2, NOER);
    k_final<<<(ESR + 255) / 256, 256, 0, stream>>>(ei_sr, ei_sr + ESR, s1, s2, b_cls, (float*)d_out);
}

// Round 4
// 665.642 us; speedup vs baseline: 8.6547x; 1.7462x over previous
//
#include <hip/hip_runtime.h>
#include <hip/hip_bf16.h>

#define NOER 100000
#define NCON 20000
#define NCLS 1000
#define FENT 64
#define HID 128
#define ESR 200000
#define EEP 400000
#define ECOV 400000
#define EBEL 100000
#define NEG 0.2f
#define NB_TOT 121000

// packed src-logit offsets (by relation)
#define SL0 0
#define SL1 NOER
#define SL2 (2*NOER)
#define SL3 (2*NOER + NCON)
#define SL4 (2*NOER + 2*NCON)
#define SL_TOT (2*NOER + 2*NCON + NCLS)
// packed dst offsets (dst-logit / CSR segment / tmp row space)
#define DL0 0
#define DL1 NOER
#define DL2 (NOER + NCON)
#define DL3 (NOER + NCON + NCLS)
#define DL4 (2*NOER + NCON + NCLS)
#define DL_TOT (2*NOER + 2*NCON + NCLS)   // 241000
#define EX_TOT 1500000
#define SCAN_B1 ((DL_TOT + 255) / 256)    // 942

typedef unsigned short u16;
typedef unsigned int u32;
typedef short v8s __attribute__((ext_vector_type(8)));
typedef float v4f __attribute__((ext_vector_type(4)));

__device__ __forceinline__ float b2f(u32 bits) { return __uint_as_float(bits << 16); }
__device__ __forceinline__ u16 f2b(float x) {
    __hip_bfloat16 h = __float2bfloat16(x);
    return *(u16*)&h;
}
__device__ __forceinline__ float wredsum(float p) {
#pragma unroll
    for (int off = 32; off; off >>= 1) p += __shfl_down(p, off);
    return p;
}

// ---------------- CSR build (unchanged from R3) ----------------
__device__ __forceinline__ void edge_decode(int e, const int* __restrict__ ep,
                                            const int* __restrict__ cov,
                                            const int* __restrict__ bel,
                                            const int* __restrict__ rcov,
                                            const int* __restrict__ rbel,
                                            int& s, int& g) {
    if (e < 500000) {
        if (e < EEP) { s = ep[e]; g = DL0 + ep[EEP + e]; }
        else { s = e - EEP; g = DL0 + s; }
    } else if (e < 900000)  { int i = e - 500000;  s = cov[i];  g = DL1 + cov[ECOV + i]; }
    else if (e < 1000000)   { int i = e - 900000;  s = bel[i];  g = DL2 + bel[EBEL + i]; }
    else if (e < 1400000)   { int i = e - 1000000; s = rcov[i]; g = DL3 + rcov[ECOV + i]; }
    else                    { int i = e - 1400000; s = rbel[i]; g = DL4 + rbel[EBEL + i]; }
}

__global__ void k_count(const int* __restrict__ ep, const int* __restrict__ cov,
                        const int* __restrict__ bel, const int* __restrict__ rcov,
                        const int* __restrict__ rbel, int* __restrict__ counts) {
    int e = blockIdx.x * blockDim.x + threadIdx.x;
    if (e >= EX_TOT) return;
    int s, g;
    edge_decode(e, ep, cov, bel, rcov, rbel, s, g);
    atomicAdd(counts + g, 1);
}

__global__ void k_scan1(const int* __restrict__ counts, int* __restrict__ part,
                        int* __restrict__ bsum) {
    __shared__ int sm[256];
    int i = blockIdx.x * 256 + threadIdx.x;
    int v = (i < DL_TOT) ? counts[i] : 0;
    sm[threadIdx.x] = v;
    __syncthreads();
#pragma unroll
    for (int off = 1; off < 256; off <<= 1) {
        int x = (threadIdx.x >= off) ? sm[threadIdx.x - off] : 0;
        __syncthreads();
        sm[threadIdx.x] += x;
        __syncthreads();
    }
    if (i < DL_TOT) part[i] = sm[threadIdx.x];
    if (threadIdx.x == 255) bsum[blockIdx.x] = sm[255];
}

__global__ void k_scan2(int* __restrict__ bsum) {
    __shared__ int sm[1024];
    int t = threadIdx.x;
    sm[t] = (t < SCAN_B1) ? bsum[t] : 0;
    __syncthreads();
#pragma unroll
    for (int off = 1; off < 1024; off <<= 1) {
        int x = (t >= off) ? sm[t - off] : 0;
        __syncthreads();
        sm[t] += x;
        __syncthreads();
    }
    if (t < SCAN_B1) bsum[t] = sm[t];
}

__global__ void k_scan3(const int* __restrict__ part, const int* __restrict__ bsum,
                        const int* __restrict__ counts, int* __restrict__ S,
                        int* __restrict__ cursor) {
    int i = blockIdx.x * 256 + threadIdx.x;
    if (i >= DL_TOT) return;
    int b = blockIdx.x;
    int s = part[i] + (b > 0 ? bsum[b - 1] : 0);
    S[i] = s;
    cursor[i] = s - counts[i];
}

__global__ void k_fill(const int* __restrict__ ep, const int* __restrict__ cov,
                       const int* __restrict__ bel, const int* __restrict__ rcov,
                       const int* __restrict__ rbel, int* __restrict__ cursor,
                       int* __restrict__ csr) {
    int e = blockIdx.x * blockDim.x + threadIdx.x;
    if (e >= EX_TOT) return;
    int s, g;
    edge_decode(e, ep, cov, bel, rcov, rbel, s, g);
    int pos = atomicAdd(cursor + g, 1);
    csr[pos] = s;
}

// ---------------- prep: bf16 casts + transposed weight stacks ----------------
__global__ void k_cast(const float* __restrict__ e_oer, const float* __restrict__ e_con,
                       const float* __restrict__ e_cls, u16* __restrict__ eb) {
    int idx = blockIdx.x * blockDim.x + threadIdx.x;
    int i4 = idx * 4;
    if (i4 >= NB_TOT * FENT) return;
    const float* src;
    if (i4 < 6400000) src = e_oer + i4;
    else if (i4 < 7680000) src = e_con + (i4 - 6400000);
    else src = e_cls + (i4 - 7680000);
    float4 v = *(const float4*)src;
    u16* d = eb + i4;
    d[0] = f2b(v.x); d[1] = f2b(v.y); d[2] = f2b(v.z); d[3] = f2b(v.w);
}

// Wt layouts: [cols=128][K] bf16, K-concat of the two relations feeding a dst type
__global__ void k_prep(const float* __restrict__ W_lin, const float* __restrict__ Wsrc,
                       const float* __restrict__ b_gat,
                       u16* __restrict__ Wlt, u16* __restrict__ Woer, u16* __restrict__ Wcon,
                       u16* __restrict__ Wcls, float* __restrict__ boer,
                       float* __restrict__ bcon, float* __restrict__ bcls2) {
    int i = blockIdx.x * 256 + threadIdx.x;
    if (i < 24576) {  // Wlt[t][c][k], k<64
        int t = i / 8192, r = i % 8192, c = r >> 6, k = r & 63;
        Wlt[i] = f2b(W_lin[t * 8192 + k * 128 + c]);
        return;
    }
    i -= 24576;
    if (i < 65536) {  // Woer[l][c][k2], k2<256: rel 0 then rel 3
        int l = i >> 15, r = i & 32767, c = r >> 8, k2 = r & 255;
        int rel = 5 * l + (k2 < 128 ? 0 : 3), k = k2 & 127;
        Woer[i] = f2b(Wsrc[(size_t)rel * 16384 + k * 128 + c]);
        return;
    }
    i -= 65536;
    if (i < 65536) {  // Wcon: rel 1 then rel 4
        int l = i >> 15, r = i & 32767, c = r >> 8, k2 = r & 255;
        int rel = 5 * l + (k2 < 128 ? 1 : 4), k = k2 & 127;
        Wcon[i] = f2b(Wsrc[(size_t)rel * 16384 + k * 128 + c]);
        return;
    }
    i -= 65536;
    if (i < 32768) {  // Wcls: rel 2
        int l = i >> 14, r = i & 16383, c = r >> 7, k = r & 127;
        Wcls[i] = f2b(Wsrc[(size_t)(5 * l + 2) * 16384 + k * 128 + c]);
        return;
    }
    i -= 32768;
    if (i < 256) { int l = i >> 7, c = i & 127;
        boer[i] = 0.5f * (b_gat[(5 * l + 0) * 128 + c] + b_gat[(5 * l + 3) * 128 + c]); return; }
    i -= 256;
    if (i < 256) { int l = i >> 7, c = i & 127;
        bcon[i] = 0.5f * (b_gat[(5 * l + 1) * 128 + c] + b_gat[(5 * l + 4) * 128 + c]); return; }
    i -= 256;
    if (i < 256) { int l = i >> 7, c = i & 127;
        bcls2[i] = b_gat[(5 * l + 2) * 128 + c]; }
}

// all 20 attention projection vectors (f32 weights)
__global__ void k_wvec(const float* __restrict__ Wsrc, const float* __restrict__ as_,
                       const float* __restrict__ Wdst, const float* __restrict__ ad,
                       float* __restrict__ wsv, float* __restrict__ wdv) {
    int a = blockIdx.x >> 5;
    int r = ((blockIdx.x & 31) << 2) + (threadIdx.x >> 6);
    int lane = threadIdx.x & 63;
    const float *W, *v;
    float* o;
    if (a < 10) { W = Wsrc + (size_t)a * HID * HID; v = as_ + a * HID; o = wsv + a * HID; }
    else { W = Wdst + (size_t)(a - 10) * HID * HID; v = ad + (a - 10) * HID; o = wdv + (a - 10) * HID; }
    float p = W[r * HID + lane] * v[lane] + W[r * HID + 64 + lane] * v[64 + lane];
    p = wredsum(p);
    if (lane == 0) o[r] = p;
}

// ---------------- MFMA GEMM: out[r,0:128] = bf16(scale * (A @ Wt^T) + bias) ----------------
struct GemmJob {
    const u16* A0;      // rows x 128 (or x K) bf16, K-half 0
    const u16* A1;      // K-half 1 (null if K<=128)
    const u16* Wt;      // [128 cols][K] bf16
    const float* bias;  // [128]
    float scale;
    int n, K;
    u16* out;           // [n][128] bf16
};

__global__ __launch_bounds__(256) void k_mgemm(GemmJob j0, GemmJob j1, GemmJob j2,
                                               int nb0, int nb1) {
    __shared__ u16 lA[64][40];
    __shared__ u16 lB[128][40];
    GemmJob J;
    int b = blockIdx.x;
    if (b < nb0) J = j0;
    else if (b < nb0 + nb1) { J = j1; b -= nb0; }
    else { J = j2; b -= nb0 + nb1; }
    const int row0 = b * 64;
    const int tid = threadIdx.x, lane = tid & 63, w = tid >> 6;
    const int wr = w >> 1, wc = w & 1;        // wave tile: rows 32*wr, cols 64*wc
    const int fr = lane & 15, kg = lane >> 4; // fragment row/col & k-group
    const int astride = J.A1 ? 128 : J.K;
    v4f acc[2][4];
#pragma unroll
    for (int i = 0; i < 2; ++i)
#pragma unroll
        for (int c = 0; c < 4; ++c) acc[i][c] = (v4f){0.f, 0.f, 0.f, 0.f};

    for (int k0 = 0; k0 < J.K; k0 += 32) {
        const u16* Asrc; int kk;
        if (k0 < 128) { Asrc = J.A0; kk = k0; } else { Asrc = J.A1; kk = k0 - 128; }
        __syncthreads();
        {   // stage A: 64 rows x 32 k
            int r = tid >> 2, seg = tid & 3;
            int gr = row0 + r;
            uint4 u = make_uint4(0u, 0u, 0u, 0u);
            if (gr < J.n) u = *(const uint4*)(Asrc + (size_t)gr * astride + kk + seg * 8);
            *(uint4*)&lA[r][seg * 8] = u;
        }
#pragma unroll
        for (int i = 0; i < 2; ++i) {  // stage B^T: 128 cols x 32 k
            int m = tid * 2 + i, c = m >> 2, seg = m & 3;
            uint4 u = *(const uint4*)(J.Wt + (size_t)c * J.K + k0 + seg * 8);
            *(uint4*)&lB[c][seg * 8] = u;
        }
        __syncthreads();
        v8s a0 = *(const v8s*)&lA[32 * wr + fr][8 * kg];
        v8s a1 = *(const v8s*)&lA[32 * wr + 16 + fr][8 * kg];
#pragma unroll
        for (int c = 0; c < 4; ++c) {
            v8s bf = *(const v8s*)&lB[64 * wc + 16 * c + fr][8 * kg];
            acc[0][c] = __builtin_amdgcn_mfma_f32_16x16x32_bf16(a0, bf, acc[0][c], 0, 0, 0);
            acc[1][c] = __builtin_amdgcn_mfma_f32_16x16x32_bf16(a1, bf, acc[1][c], 0, 0, 0);
        }
    }
#pragma unroll
    for (int i = 0; i < 2; ++i)
#pragma unroll
        for (int c = 0; c < 4; ++c) {
            int col = 64 * wc + 16 * c + fr;
            float bv = J.bias[col];
#pragma unroll
            for (int jj = 0; jj < 4; ++jj) {
                int gr = row0 + 32 * wr + 16 * i + 4 * kg + jj;
                if (gr < J.n) J.out[(size_t)gr * 128 + col] = f2b(acc[i][c][jj] * J.scale + bv);
            }
        }
}

// ---------------- per-node logit dots (all types, one launch) ----------------
__global__ void k_dots_all(const u16* __restrict__ hb, const float* __restrict__ wsv,
                           const float* __restrict__ wdv, float* __restrict__ slp,
                           float* __restrict__ dlp, int lb) {
    int t = blockIdx.x * blockDim.x + threadIdx.x;
    int n = t >> 6, lane = t & 63;
    if (n >= NB_TOT) return;
    const u32* h;
    int m;
    const float *v0, *v1, *v2, *v3;
    float *o0, *o1, *o2, *o3;
    if (n < NOER) {
        m = n; h = (const u32*)hb;
        v0 = wsv + (lb + 0) * HID; o0 = slp + SL0 + m;
        v1 = wsv + (lb + 1) * HID; o1 = slp + SL1 + m;
        v2 = wdv + (lb + 0) * HID; o2 = dlp + DL0 + m;
        v3 = wdv + (lb + 3) * HID; o3 = dlp + DL3 + m;
    } else if (n < NOER + NCON) {
        m = n - NOER; h = (const u32*)(hb + (size_t)NOER * HID);
        v0 = wsv + (lb + 2) * HID; o0 = slp + SL2 + m;
        v1 = wsv + (lb + 3) * HID; o1 = slp + SL3 + m;
        v2 = wdv + (lb + 1) * HID; o2 = dlp + DL1 + m;
        v3 = wdv + (lb + 4) * HID; o3 = dlp + DL4 + m;
    } else {
        m = n - NOER - NCON; h = (const u32*)(hb + (size_t)(NOER + NCON) * HID);
        v0 = wsv + (lb + 4) * HID; o0 = slp + SL4 + m;
        v1 = wdv + (lb + 2) * HID; o1 = dlp + DL2 + m;
        v2 = nullptr; o2 = nullptr; v3 = nullptr; o3 = nullptr;
    }
    u32 hu = h[(size_t)m * 64 + lane];
    float h0 = b2f(hu & 0xffffu), h1 = b2f(hu >> 16);
    float p0 = 0.f, p1 = 0.f, p2 = 0.f, p3 = 0.f;
    {
        float2 a = *(const float2*)(v0 + 2 * lane);
        p0 = h0 * a.x + h1 * a.y;
    }
    {
        float2 a = *(const float2*)(v1 + 2 * lane);
        p1 = h0 * a.x + h1 * a.y;
    }
    if (v2) { float2 a = *(const float2*)(v2 + 2 * lane); p2 = h0 * a.x + h1 * a.y; }
    if (v3) { float2 a = *(const float2*)(v3 + 2 * lane); p3 = h0 * a.x + h1 * a.y; }
    p0 = wredsum(p0); p1 = wredsum(p1); p2 = wredsum(p2); p3 = wredsum(p3);
    if (lane == 0) {
        o0[0] = p0; o1[0] = p1;
        if (o2) o2[0] = p2;
        if (o3) o3[0] = p3;
    }
}

// ---------------- fused GAT aggregation over raw h (all 5 relations) ----------------
__global__ __launch_bounds__(256) void k_agg_all(const int* __restrict__ csr,
                                                 const int* __restrict__ S,
                                                 const float* __restrict__ slp,
                                                 const float* __restrict__ dlp,
                                                 const u16* __restrict__ hb,
                                                 u16* __restrict__ tmp) {
    int g = blockIdx.x * 4 + (threadIdx.x >> 6);
    if (g >= DL_TOT) return;
    int lane = threadIdx.x & 63;
    const u32* h;
    int sb;
    if (g < DL1)      { h = (const u32*)hb; sb = SL0; }
    else if (g < DL2) { h = (const u32*)hb; sb = SL1; }
    else if (g < DL3) { h = (const u32*)(hb + (size_t)NOER * HID); sb = SL2; }
    else if (g < DL4) { h = (const u32*)(hb + (size_t)NOER * HID); sb = SL3; }
    else              { h = (const u32*)(hb + (size_t)(NOER + NCON) * HID); sb = SL4; }
    int beg = (g == 0) ? 0 : S[g - 1];
    int end = S[g];
    float dlv = dlp[g];
    float a0 = 0.f, a1 = 0.f, den = 0.f;
    for (int i = beg; i < end; ++i) {
        int s = csr[i];
        float lg = slp[sb + s] + dlv;
        lg = lg > 0.f ? lg : NEG * lg;
        float ex = expf(lg);
        u32 hu = h[(size_t)s * 64 + lane];
        a0 = fmaf(ex, b2f(hu & 0xffffu), a0);
        a1 = fmaf(ex, b2f(hu >> 16), a1);
        den += ex;
    }
    float inv = (end > beg) ? 1.f / den : 0.f;
    u32 r = (u32)f2b(a0 * inv) | ((u32)f2b(a1 * inv) << 16);
    ((u32*)tmp)[(size_t)g * 64 + lane] = r;
}

// ---------------- classifier ----------------
__global__ void k_score(const float* __restrict__ x, const u16* __restrict__ hb,
                        const float* __restrict__ Wc, float* __restrict__ s1,
                        float* __restrict__ s2) {
    int t = blockIdx.x * blockDim.x + threadIdx.x;
    int n = t >> 6, lane = t & 63;
    if (n >= NOER) return;
    float xv = x[(size_t)n * FENT + lane];
    u32 hu = ((const u32*)hb)[(size_t)n * 64 + lane];
    float h0 = b2f(hu & 0xffffu), h1 = b2f(hu >> 16);
    float2 wa = *(const float2*)(Wc + 64 + 2 * lane);
    float2 wb = *(const float2*)(Wc + 256 + 2 * lane);
    float p1 = xv * Wc[lane] + h0 * wa.x + h1 * wa.y;
    float p2 = xv * Wc[192 + lane] + h0 * wb.x + h1 * wb.y;
#pragma unroll
    for (int off = 32; off; off >>= 1) { p1 += __shfl_down(p1, off); p2 += __shfl_down(p2, off); }
    if (lane == 0) { s1[n] = p1; s2[n] = p2; }
}

__global__ void k_final(const int* __restrict__ src, const int* __restrict__ dst,
                        const float* __restrict__ s1, const float* __restrict__ s2,
                        const float* __restrict__ bcls, float* __restrict__ out) {
    int e = blockIdx.x * blockDim.x + threadIdx.x;
    if (e >= ESR) return;
    out[e] = s1[src[e]] + s2[dst[e]] + bcls[0];
}

extern "C" void kernel_launch(void* const* d_in, const int* in_sizes, int n_in,
                              void* d_out, int out_size, void* d_ws, size_t ws_size,
                              hipStream_t stream) {
    const float* x_oer   = (const float*)d_in[0];
    const float* e_oer   = (const float*)d_in[3];
    const float* e_con   = (const float*)d_in[4];
    const float* e_cls   = (const float*)d_in[5];
    const float* W_lin   = (const float*)d_in[6];
    const float* b_lin   = (const float*)d_in[7];
    const float* Wsrc    = (const float*)d_in[8];
    const float* Wdst    = (const float*)d_in[9];
    const float* att_src = (const float*)d_in[10];
    const float* att_dst = (const float*)d_in[11];
    const float* b_gat   = (const float*)d_in[12];
    const float* W_cls   = (const float*)d_in[13];
    const float* b_cls   = (const float*)d_in[14];
    const int* ei_sr   = (const int*)d_in[15];
    const int* ei_cov  = (const int*)d_in[16];
    const int* ei_bel  = (const int*)d_in[17];
    const int* ei_rcov = (const int*)d_in[18];
    const int* ei_rbel = (const int*)d_in[19];
    const int* ei_ep   = (const int*)d_in[20];

    float* ws = (float*)d_ws;
    size_t o = 0;
    u16* hb  = (u16*)(ws + o); o += (size_t)NB_TOT * HID / 2;   // bf16 [121000][128]
    u16* eb  = (u16*)(ws + o); o += (size_t)NB_TOT * FENT / 2;  // bf16 [121000][64]
    u16* tmp = (u16*)(ws + o); o += (size_t)DL_TOT * HID / 2;   // bf16 [241000][128]
    float* slp  = ws + o; o += SL_TOT;
    float* dlp  = ws + o; o += DL_TOT;
    float* wsv  = ws + o; o += 10 * HID;
    float* wdv  = ws + o; o += 10 * HID;
    u16* Wlt  = (u16*)(ws + o); o += 3 * HID * FENT / 2;
    u16* Woer = (u16*)(ws + o); o += 2 * HID * 256 / 2;
    u16* Wcon = (u16*)(ws + o); o += 2 * HID * 256 / 2;
    u16* Wcls = (u16*)(ws + o); o += 2 * HID * HID / 2;
    float* boer  = ws + o; o += 2 * HID;
    float* bcon  = ws + o; o += 2 * HID;
    float* bcls2 = ws + o; o += 2 * HID;
    float* s1 = ws + o; o += NOER;
    float* s2 = ws + o; o += NOER;
    int* counts = (int*)(ws + o); o += DL_TOT;
    int* part   = (int*)(ws + o); o += DL_TOT;
    int* S      = (int*)(ws + o); o += DL_TOT;
    int* cursor = (int*)(ws + o); o += DL_TOT;
    int* bsum   = (int*)(ws + o); o += 1024;
    int* csr    = (int*)(ws + o); o += EX_TOT;

    u16* hb_con = hb + (size_t)NOER * HID;
    u16* hb_cls = hb + (size_t)(NOER + NCON) * HID;

    // ---- CSR build ----
    hipMemsetAsync(counts, 0, DL_TOT * sizeof(int), stream);
    k_count<<<(EX_TOT + 255) / 256, 256, 0, stream>>>(ei_ep, ei_cov, ei_bel, ei_rcov, ei_rbel, counts);
    k_scan1<<<SCAN_B1, 256, 0, stream>>>(counts, part, bsum);
    k_scan2<<<1, 1024, 0, stream>>>(bsum);
    k_scan3<<<SCAN_B1, 256, 0, stream>>>(part, bsum, counts, S, cursor);
    k_fill<<<(EX_TOT + 255) / 256, 256, 0, stream>>>(ei_ep, ei_cov, ei_bel, ei_rcov, ei_rbel, cursor, csr);

    // ---- prep ----
    k_prep<<<739, 256, 0, stream>>>(W_lin, Wsrc, b_gat, Wlt, Woer, Wcon, Wcls, boer, bcon, bcls2);
    k_cast<<<(NB_TOT * FENT / 4 + 255) / 256, 256, 0, stream>>>(e_oer, e_con, e_cls, eb);
    k_wvec<<<640, 256, 0, stream>>>(Wsrc, att_src, Wdst, att_dst, wsv, wdv);

    // ---- input projections (one fused MFMA launch) ----
    {
        GemmJob ja = {eb, nullptr, Wlt, b_lin, 1.f, NOER, FENT, hb};
        GemmJob jb = {eb + (size_t)NOER * FENT, nullptr, Wlt + 8192, b_lin + 128, 1.f, NCON, FENT, hb_con};
        GemmJob jc = {eb + (size_t)(NOER + NCON) * FENT, nullptr, Wlt + 16384, b_lin + 256, 1.f, NCLS, FENT, hb_cls};
        k_mgemm<<<1563 + 313 + 16, 256, 0, stream>>>(ja, jb, jc, 1563, 313);
    }

    for (int l = 0; l < 2; ++l) {
        int lb = l * 5;
        k_dots_all<<<NB_TOT * 64 / 256, 256, 0, stream>>>(hb, wsv, wdv, slp, dlp, lb);
        k_agg_all<<<DL_TOT / 4, 256, 0, stream>>>(csr, S, slp, dlp, hb, tmp);
        GemmJob ja = {tmp + (size_t)DL0 * HID, tmp + (size_t)DL3 * HID,
                      Woer + l * 32768, boer + l * HID, 0.5f, NOER, 256, hb};
        GemmJob jb = {tmp + (size_t)DL1 * HID, tmp + (size_t)DL4 * HID,
                      Wcon + l * 32768, bcon + l * HID, 0.5f, NCON, 256, hb_con};
        GemmJob jc = {tmp + (size_t)DL2 * HID, nullptr,
                      Wcls + l * 16384, bcls2 + l * HID, 1.f, NCLS, 128, hb_cls};
        k_mgemm<<<1563 + 313 + 16, 256, 0, stream>>>(ja, jb, jc, 1563, 313);
    }

    k_score<<<(NOER * 64 + 255) / 256, 256, 0, stream>>>(x_oer, hb, W_cls, s1, s2);
    k_final<<<(ESR + 255) / 256, 256, 0, stream>>>(ei_sr, ei_sr + ESR, s1, s2, b_cls, (float*)d_out);
}

// Round 5
// 579.838 us; speedup vs baseline: 9.9354x; 1.1480x over previous
//
#include <hip/hip_runtime.h>
#include <hip/hip_bf16.h>

#define NOER 100000
#define NCON 20000
#define NCLS 1000
#define FENT 64
#define HID 128
#define ESR 200000
#define EEP 400000
#define ECOV 400000
#define EBEL 100000
#define NEG 0.2f
#define NB_TOT 121000

// packed src-logit offsets (by relation)
#define SL0 0
#define SL1 NOER
#define SL2 (2*NOER)
#define SL3 (2*NOER + NCON)
#define SL4 (2*NOER + 2*NCON)
#define SL_TOT (2*NOER + 2*NCON + NCLS)
// packed dst offsets (dst-logit / CSR segment / tmp row space)
#define DL0 0
#define DL1 NOER
#define DL2 (NOER + NCON)
#define DL3 (NOER + NCON + NCLS)
#define DL4 (2*NOER + NCON + NCLS)
#define DL_TOT (2*NOER + 2*NCON + NCLS)   // 241000
#define EX_TOT 1500000
#define SCAN_B1 ((DL_TOT + 255) / 256)    // 942

typedef unsigned short u16;
typedef unsigned int u32;
typedef short v8s __attribute__((ext_vector_type(8)));
typedef float v4f __attribute__((ext_vector_type(4)));

__device__ __forceinline__ float b2f(u32 bits) { return __uint_as_float(bits << 16); }
__device__ __forceinline__ u16 f2b(float x) {
    __hip_bfloat16 h = __float2bfloat16(x);
    return *(u16*)&h;
}
__device__ __forceinline__ float wredsum(float p) {
#pragma unroll
    for (int off = 32; off; off >>= 1) p += __shfl_down(p, off);
    return p;
}

// ---------------- CSR build ----------------
__device__ __forceinline__ void edge_decode(int e, const int* __restrict__ ep,
                                            const int* __restrict__ cov,
                                            const int* __restrict__ bel,
                                            const int* __restrict__ rcov,
                                            const int* __restrict__ rbel,
                                            int& s, int& g) {
    if (e < 500000) {
        if (e < EEP) { s = ep[e]; g = DL0 + ep[EEP + e]; }
        else { s = e - EEP; g = DL0 + s; }
    } else if (e < 900000)  { int i = e - 500000;  s = cov[i];  g = DL1 + cov[ECOV + i]; }
    else if (e < 1000000)   { int i = e - 900000;  s = bel[i];  g = DL2 + bel[EBEL + i]; }
    else if (e < 1400000)   { int i = e - 1000000; s = rcov[i]; g = DL3 + rcov[ECOV + i]; }
    else                    { int i = e - 1400000; s = rbel[i]; g = DL4 + rbel[EBEL + i]; }
}

__global__ void k_count(const int* __restrict__ ep, const int* __restrict__ cov,
                        const int* __restrict__ bel, const int* __restrict__ rcov,
                        const int* __restrict__ rbel, int* __restrict__ counts) {
    int e = blockIdx.x * blockDim.x + threadIdx.x;
    if (e >= EX_TOT) return;
    int s, g;
    edge_decode(e, ep, cov, bel, rcov, rbel, s, g);
    atomicAdd(counts + g, 1);
}

__global__ void k_scan1(const int* __restrict__ counts, int* __restrict__ part,
                        int* __restrict__ bsum) {
    __shared__ int sm[256];
    int i = blockIdx.x * 256 + threadIdx.x;
    int v = (i < DL_TOT) ? counts[i] : 0;
    sm[threadIdx.x] = v;
    __syncthreads();
#pragma unroll
    for (int off = 1; off < 256; off <<= 1) {
        int x = (threadIdx.x >= off) ? sm[threadIdx.x - off] : 0;
        __syncthreads();
        sm[threadIdx.x] += x;
        __syncthreads();
    }
    if (i < DL_TOT) part[i] = sm[threadIdx.x];
    if (threadIdx.x == 255) bsum[blockIdx.x] = sm[255];
}

__global__ void k_scan2(int* __restrict__ bsum) {
    __shared__ int sm[1024];
    int t = threadIdx.x;
    sm[t] = (t < SCAN_B1) ? bsum[t] : 0;
    __syncthreads();
#pragma unroll
    for (int off = 1; off < 1024; off <<= 1) {
        int x = (t >= off) ? sm[t - off] : 0;
        __syncthreads();
        sm[t] += x;
        __syncthreads();
    }
    if (t < SCAN_B1) bsum[t] = sm[t];
}

__global__ void k_scan3(const int* __restrict__ part, const int* __restrict__ bsum,
                        const int* __restrict__ counts, int* __restrict__ S,
                        int* __restrict__ cursor) {
    int i = blockIdx.x * 256 + threadIdx.x;
    if (i >= DL_TOT) return;
    int b = blockIdx.x;
    int s = part[i] + (b > 0 ? bsum[b - 1] : 0);
    S[i] = s;
    cursor[i] = s - counts[i];
}

__global__ void k_fill(const int* __restrict__ ep, const int* __restrict__ cov,
                       const int* __restrict__ bel, const int* __restrict__ rcov,
                       const int* __restrict__ rbel, int* __restrict__ cursor,
                       int* __restrict__ csr) {
    int e = blockIdx.x * blockDim.x + threadIdx.x;
    if (e >= EX_TOT) return;
    int s, g;
    edge_decode(e, ep, cov, bel, rcov, rbel, s, g);
    int pos = atomicAdd(cursor + g, 1);
    csr[pos] = s;
}

// ---------------- prep: bf16 casts + transposed weight stacks ----------------
__global__ void k_cast(const float* __restrict__ e_oer, const float* __restrict__ e_con,
                       const float* __restrict__ e_cls, u16* __restrict__ eb) {
    int idx = blockIdx.x * blockDim.x + threadIdx.x;
    int i4 = idx * 4;
    if (i4 >= NB_TOT * FENT) return;
    const float* src;
    if (i4 < 6400000) src = e_oer + i4;
    else if (i4 < 7680000) src = e_con + (i4 - 6400000);
    else src = e_cls + (i4 - 7680000);
    float4 v = *(const float4*)src;
    u16* d = eb + i4;
    d[0] = f2b(v.x); d[1] = f2b(v.y); d[2] = f2b(v.z); d[3] = f2b(v.w);
}

// Wt layouts: [cols=128][K] bf16, K-concat of the two relations feeding a dst type
__global__ void k_prep(const float* __restrict__ W_lin, const float* __restrict__ Wsrc,
                       const float* __restrict__ b_gat,
                       u16* __restrict__ Wlt, u16* __restrict__ Woer, u16* __restrict__ Wcon,
                       u16* __restrict__ Wcls, float* __restrict__ boer,
                       float* __restrict__ bcon, float* __restrict__ bcls2) {
    int i = blockIdx.x * 256 + threadIdx.x;
    if (i < 24576) {
        int t = i / 8192, r = i % 8192, c = r >> 6, k = r & 63;
        Wlt[i] = f2b(W_lin[t * 8192 + k * 128 + c]);
        return;
    }
    i -= 24576;
    if (i < 65536) {
        int l = i >> 15, r = i & 32767, c = r >> 8, k2 = r & 255;
        int rel = 5 * l + (k2 < 128 ? 0 : 3), k = k2 & 127;
        Woer[i] = f2b(Wsrc[(size_t)rel * 16384 + k * 128 + c]);
        return;
    }
    i -= 65536;
    if (i < 65536) {
        int l = i >> 15, r = i & 32767, c = r >> 8, k2 = r & 255;
        int rel = 5 * l + (k2 < 128 ? 1 : 4), k = k2 & 127;
        Wcon[i] = f2b(Wsrc[(size_t)rel * 16384 + k * 128 + c]);
        return;
    }
    i -= 65536;
    if (i < 32768) {
        int l = i >> 14, r = i & 16383, c = r >> 7, k = r & 127;
        Wcls[i] = f2b(Wsrc[(size_t)(5 * l + 2) * 16384 + k * 128 + c]);
        return;
    }
    i -= 32768;
    if (i < 256) { int l = i >> 7, c = i & 127;
        boer[i] = 0.5f * (b_gat[(5 * l + 0) * 128 + c] + b_gat[(5 * l + 3) * 128 + c]); return; }
    i -= 256;
    if (i < 256) { int l = i >> 7, c = i & 127;
        bcon[i] = 0.5f * (b_gat[(5 * l + 1) * 128 + c] + b_gat[(5 * l + 4) * 128 + c]); return; }
    i -= 256;
    if (i < 256) { int l = i >> 7, c = i & 127;
        bcls2[i] = b_gat[(5 * l + 2) * 128 + c]; }
}

// all 20 attention projection vectors (f32 weights)
__global__ void k_wvec(const float* __restrict__ Wsrc, const float* __restrict__ as_,
                       const float* __restrict__ Wdst, const float* __restrict__ ad,
                       float* __restrict__ wsv, float* __restrict__ wdv) {
    int a = blockIdx.x >> 5;
    int r = ((blockIdx.x & 31) << 2) + (threadIdx.x >> 6);
    int lane = threadIdx.x & 63;
    const float *W, *v;
    float* o;
    if (a < 10) { W = Wsrc + (size_t)a * HID * HID; v = as_ + a * HID; o = wsv + a * HID; }
    else { W = Wdst + (size_t)(a - 10) * HID * HID; v = ad + (a - 10) * HID; o = wdv + (a - 10) * HID; }
    float p = W[r * HID + lane] * v[lane] + W[r * HID + 64 + lane] * v[64 + lane];
    p = wredsum(p);
    if (lane == 0) o[r] = p;
}

// ---------------- MFMA GEMM: out[r,0:128] = bf16(scale * (A @ Wt^T) + bias) ----------------
struct GemmJob {
    const u16* A0;
    const u16* A1;
    const u16* Wt;
    const float* bias;
    float scale;
    int n, K;
    u16* out;
};

__global__ __launch_bounds__(256) void k_mgemm(GemmJob j0, GemmJob j1, GemmJob j2,
                                               int nb0, int nb1) {
    __shared__ u16 lA[64][40];
    __shared__ u16 lB[128][40];
    GemmJob J;
    int b = blockIdx.x;
    if (b < nb0) J = j0;
    else if (b < nb0 + nb1) { J = j1; b -= nb0; }
    else { J = j2; b -= nb0 + nb1; }
    const int row0 = b * 64;
    const int tid = threadIdx.x, lane = tid & 63, w = tid >> 6;
    const int wr = w >> 1, wc = w & 1;
    const int fr = lane & 15, kg = lane >> 4;
    const int astride = J.A1 ? 128 : J.K;
    v4f acc[2][4];
#pragma unroll
    for (int i = 0; i < 2; ++i)
#pragma unroll
        for (int c = 0; c < 4; ++c) acc[i][c] = (v4f){0.f, 0.f, 0.f, 0.f};

    for (int k0 = 0; k0 < J.K; k0 += 32) {
        const u16* Asrc; int kk;
        if (k0 < 128) { Asrc = J.A0; kk = k0; } else { Asrc = J.A1; kk = k0 - 128; }
        __syncthreads();
        {
            int r = tid >> 2, seg = tid & 3;
            int gr = row0 + r;
            uint4 u = make_uint4(0u, 0u, 0u, 0u);
            if (gr < J.n) u = *(const uint4*)(Asrc + (size_t)gr * astride + kk + seg * 8);
            *(uint4*)&lA[r][seg * 8] = u;
        }
#pragma unroll
        for (int i = 0; i < 2; ++i) {
            int m = tid * 2 + i, c = m >> 2, seg = m & 3;
            uint4 u = *(const uint4*)(J.Wt + (size_t)c * J.K + k0 + seg * 8);
            *(uint4*)&lB[c][seg * 8] = u;
        }
        __syncthreads();
        v8s a0 = *(const v8s*)&lA[32 * wr + fr][8 * kg];
        v8s a1 = *(const v8s*)&lA[32 * wr + 16 + fr][8 * kg];
#pragma unroll
        for (int c = 0; c < 4; ++c) {
            v8s bf = *(const v8s*)&lB[64 * wc + 16 * c + fr][8 * kg];
            acc[0][c] = __builtin_amdgcn_mfma_f32_16x16x32_bf16(a0, bf, acc[0][c], 0, 0, 0);
            acc[1][c] = __builtin_amdgcn_mfma_f32_16x16x32_bf16(a1, bf, acc[1][c], 0, 0, 0);
        }
    }
#pragma unroll
    for (int i = 0; i < 2; ++i)
#pragma unroll
        for (int c = 0; c < 4; ++c) {
            int col = 64 * wc + 16 * c + fr;
            float bv = J.bias[col];
#pragma unroll
            for (int jj = 0; jj < 4; ++jj) {
                int gr = row0 + 32 * wr + 16 * i + 4 * kg + jj;
                if (gr < J.n) J.out[(size_t)gr * 128 + col] = f2b(acc[i][c][jj] * J.scale + bv);
            }
        }
}

// ---------------- per-node logit dots ----------------
__global__ void k_dots_all(const u16* __restrict__ hb, const float* __restrict__ wsv,
                           const float* __restrict__ wdv, float* __restrict__ slp,
                           float* __restrict__ dlp, int lb) {
    int t = blockIdx.x * blockDim.x + threadIdx.x;
    int n = t >> 6, lane = t & 63;
    if (n >= NB_TOT) return;
    const u32* h;
    int m;
    const float *v0, *v1, *v2, *v3;
    float *o0, *o1, *o2, *o3;
    if (n < NOER) {
        m = n; h = (const u32*)hb;
        v0 = wsv + (lb + 0) * HID; o0 = slp + SL0 + m;
        v1 = wsv + (lb + 1) * HID; o1 = slp + SL1 + m;
        v2 = wdv + (lb + 0) * HID; o2 = dlp + DL0 + m;
        v3 = wdv + (lb + 3) * HID; o3 = dlp + DL3 + m;
    } else if (n < NOER + NCON) {
        m = n - NOER; h = (const u32*)(hb + (size_t)NOER * HID);
        v0 = wsv + (lb + 2) * HID; o0 = slp + SL2 + m;
        v1 = wsv + (lb + 3) * HID; o1 = slp + SL3 + m;
        v2 = wdv + (lb + 1) * HID; o2 = dlp + DL1 + m;
        v3 = wdv + (lb + 4) * HID; o3 = dlp + DL4 + m;
    } else {
        m = n - NOER - NCON; h = (const u32*)(hb + (size_t)(NOER + NCON) * HID);
        v0 = wsv + (lb + 4) * HID; o0 = slp + SL4 + m;
        v1 = wdv + (lb + 2) * HID; o1 = dlp + DL2 + m;
        v2 = nullptr; o2 = nullptr; v3 = nullptr; o3 = nullptr;
    }
    u32 hu = h[(size_t)m * 64 + lane];
    float h0 = b2f(hu & 0xffffu), h1 = b2f(hu >> 16);
    float p0 = 0.f, p1 = 0.f, p2 = 0.f, p3 = 0.f;
    { float2 a = *(const float2*)(v0 + 2 * lane); p0 = h0 * a.x + h1 * a.y; }
    { float2 a = *(const float2*)(v1 + 2 * lane); p1 = h0 * a.x + h1 * a.y; }
    if (v2) { float2 a = *(const float2*)(v2 + 2 * lane); p2 = h0 * a.x + h1 * a.y; }
    if (v3) { float2 a = *(const float2*)(v3 + 2 * lane); p3 = h0 * a.x + h1 * a.y; }
    p0 = wredsum(p0); p1 = wredsum(p1); p2 = wredsum(p2); p3 = wredsum(p3);
    if (lane == 0) {
        o0[0] = p0; o1[0] = p1;
        if (o2) o2[0] = p2;
        if (o3) o3[0] = p3;
    }
}

// ---------------- fused GAT aggregation, latency-optimized ----------------
// Per 64-edge chunk: lane j prefetches csr[beg+j] and computes ex_j (one lane-parallel
// gather). Inner loop shfl-broadcasts (s_j, ex_j); h-row gathers are then
// address-independent across iterations -> unroll 4 keeps multiple in flight.
__global__ __launch_bounds__(256) void k_agg_all(const int* __restrict__ csr,
                                                 const int* __restrict__ S,
                                                 const float* __restrict__ slp,
                                                 const float* __restrict__ dlp,
                                                 const u16* __restrict__ hb,
                                                 u16* __restrict__ tmp) {
    int g = blockIdx.x * 4 + (threadIdx.x >> 6);
    if (g >= DL_TOT) return;
    int lane = threadIdx.x & 63;
    const u32* h;
    int sb;
    if (g < DL1)      { h = (const u32*)hb; sb = SL0; }
    else if (g < DL2) { h = (const u32*)hb; sb = SL1; }
    else if (g < DL3) { h = (const u32*)(hb + (size_t)NOER * HID); sb = SL2; }
    else if (g < DL4) { h = (const u32*)(hb + (size_t)NOER * HID); sb = SL3; }
    else              { h = (const u32*)(hb + (size_t)(NOER + NCON) * HID); sb = SL4; }
    int beg = (g == 0) ? 0 : S[g - 1];
    int end = S[g];
    float dlv = dlp[g];
    float a0 = 0.f, a1 = 0.f, den = 0.f;
    for (int c0 = beg; c0 < end; c0 += 64) {
        int nchunk = end - c0;
        if (nchunk > 64) nchunk = 64;
        int s_l = 0;
        float ex_l = 0.f;
        if (lane < nchunk) {
            s_l = csr[c0 + lane];
            float lg = slp[sb + s_l] + dlv;
            lg = lg > 0.f ? lg : NEG * lg;
            ex_l = expf(lg);
        }
#pragma unroll 4
        for (int j = 0; j < nchunk; ++j) {
            int s = __shfl(s_l, j);
            float ex = __shfl(ex_l, j);
            u32 hu = h[(size_t)s * 64 + lane];
            a0 = fmaf(ex, b2f(hu & 0xffffu), a0);
            a1 = fmaf(ex, b2f(hu >> 16), a1);
            den += ex;
        }
    }
    float inv = (end > beg) ? 1.f / den : 0.f;
    u32 r = (u32)f2b(a0 * inv) | ((u32)f2b(a1 * inv) << 16);
    ((u32*)tmp)[(size_t)g * 64 + lane] = r;
}

// ---------------- classifier ----------------
__global__ void k_score(const float* __restrict__ x, const u16* __restrict__ hb,
                        const float* __restrict__ Wc, float* __restrict__ s1,
                        float* __restrict__ s2) {
    int t = blockIdx.x * blockDim.x + threadIdx.x;
    int n = t >> 6, lane = t & 63;
    if (n >= NOER) return;
    float xv = x[(size_t)n * FENT + lane];
    u32 hu = ((const u32*)hb)[(size_t)n * 64 + lane];
    float h0 = b2f(hu & 0xffffu), h1 = b2f(hu >> 16);
    float2 wa = *(const float2*)(Wc + 64 + 2 * lane);
    float2 wb = *(const float2*)(Wc + 256 + 2 * lane);
    float p1 = xv * Wc[lane] + h0 * wa.x + h1 * wa.y;
    float p2 = xv * Wc[192 + lane] + h0 * wb.x + h1 * wb.y;
#pragma unroll
    for (int off = 32; off; off >>= 1) { p1 += __shfl_down(p1, off); p2 += __shfl_down(p2, off); }
    if (lane == 0) { s1[n] = p1; s2[n] = p2; }
}

__global__ void k_final(const int* __restrict__ src, const int* __restrict__ dst,
                        const float* __restrict__ s1, const float* __restrict__ s2,
                        const float* __restrict__ bcls, float* __restrict__ out) {
    int e = blockIdx.x * blockDim.x + threadIdx.x;
    if (e >= ESR) return;
    out[e] = s1[src[e]] + s2[dst[e]] + bcls[0];
}

extern "C" void kernel_launch(void* const* d_in, const int* in_sizes, int n_in,
                              void* d_out, int out_size, void* d_ws, size_t ws_size,
                              hipStream_t stream) {
    const float* x_oer   = (const float*)d_in[0];
    const float* e_oer   = (const float*)d_in[3];
    const float* e_con   = (const float*)d_in[4];
    const float* e_cls   = (const float*)d_in[5];
    const float* W_lin   = (const float*)d_in[6];
    const float* b_lin   = (const float*)d_in[7];
    const float* Wsrc    = (const float*)d_in[8];
    const float* Wdst    = (const float*)d_in[9];
    const float* att_src = (const float*)d_in[10];
    const float* att_dst = (const float*)d_in[11];
    const float* b_gat   = (const float*)d_in[12];
    const float* W_cls   = (const float*)d_in[13];
    const float* b_cls   = (const float*)d_in[14];
    const int* ei_sr   = (const int*)d_in[15];
    const int* ei_cov  = (const int*)d_in[16];
    const int* ei_bel  = (const int*)d_in[17];
    const int* ei_rcov = (const int*)d_in[18];
    const int* ei_rbel = (const int*)d_in[19];
    const int* ei_ep   = (const int*)d_in[20];

    float* ws = (float*)d_ws;
    size_t o = 0;
    u16* hb  = (u16*)(ws + o); o += (size_t)NB_TOT * HID / 2;
    u16* eb  = (u16*)(ws + o); o += (size_t)NB_TOT * FENT / 2;
    u16* tmp = (u16*)(ws + o); o += (size_t)DL_TOT * HID / 2;
    float* slp  = ws + o; o += SL_TOT;
    float* dlp  = ws + o; o += DL_TOT;
    float* wsv  = ws + o; o += 10 * HID;
    float* wdv  = ws + o; o += 10 * HID;
    u16* Wlt  = (u16*)(ws + o); o += 3 * HID * FENT / 2;
    u16* Woer = (u16*)(ws + o); o += 2 * HID * 256 / 2;
    u16* Wcon = (u16*)(ws + o); o += 2 * HID * 256 / 2;
    u16* Wcls = (u16*)(ws + o); o += 2 * HID * HID / 2;
    float* boer  = ws + o; o += 2 * HID;
    float* bcon  = ws + o; o += 2 * HID;
    float* bcls2 = ws + o; o += 2 * HID;
    float* s1 = ws + o; o += NOER;
    float* s2 = ws + o; o += NOER;
    int* counts = (int*)(ws + o); o += DL_TOT;
    int* part   = (int*)(ws + o); o += DL_TOT;
    int* S      = (int*)(ws + o); o += DL_TOT;
    int* cursor = (int*)(ws + o); o += DL_TOT;
    int* bsum   = (int*)(ws + o); o += 1024;
    int* csr    = (int*)(ws + o); o += EX_TOT;

    u16* hb_con = hb + (size_t)NOER * HID;
    u16* hb_cls = hb + (size_t)(NOER + NCON) * HID;

    // ---- CSR build ----
    hipMemsetAsync(counts, 0, DL_TOT * sizeof(int), stream);
    k_count<<<(EX_TOT + 255) / 256, 256, 0, stream>>>(ei_ep, ei_cov, ei_bel, ei_rcov, ei_rbel, counts);
    k_scan1<<<SCAN_B1, 256, 0, stream>>>(counts, part, bsum);
    k_scan2<<<1, 1024, 0, stream>>>(bsum);
    k_scan3<<<SCAN_B1, 256, 0, stream>>>(part, bsum, counts, S, cursor);
    k_fill<<<(EX_TOT + 255) / 256, 256, 0, stream>>>(ei_ep, ei_cov, ei_bel, ei_rcov, ei_rbel, cursor, csr);

    // ---- prep ----
    k_prep<<<739, 256, 0, stream>>>(W_lin, Wsrc, b_gat, Wlt, Woer, Wcon, Wcls, boer, bcon, bcls2);
    k_cast<<<(NB_TOT * FENT / 4 + 255) / 256, 256, 0, stream>>>(e_oer, e_con, e_cls, eb);
    k_wvec<<<640, 256, 0, stream>>>(Wsrc, att_src, Wdst, att_dst, wsv, wdv);

    // ---- input projections ----
    {
        GemmJob ja = {eb, nullptr, Wlt, b_lin, 1.f, NOER, FENT, hb};
        GemmJob jb = {eb + (size_t)NOER * FENT, nullptr, Wlt + 8192, b_lin + 128, 1.f, NCON, FENT, hb_con};
        GemmJob jc = {eb + (size_t)(NOER + NCON) * FENT, nullptr, Wlt + 16384, b_lin + 256, 1.f, NCLS, FENT, hb_cls};
        k_mgemm<<<1563 + 313 + 16, 256, 0, stream>>>(ja, jb, jc, 1563, 313);
    }

    for (int l = 0; l < 2; ++l) {
        int lb = l * 5;
        k_dots_all<<<NB_TOT * 64 / 256, 256, 0, stream>>>(hb, wsv, wdv, slp, dlp, lb);
        k_agg_all<<<DL_TOT / 4, 256, 0, stream>>>(csr, S, slp, dlp, hb, tmp);
        GemmJob ja = {tmp + (size_t)DL0 * HID, tmp + (size_t)DL3 * HID,
                      Woer + l * 32768, boer + l * HID, 0.5f, NOER, 256, hb};
        GemmJob jb = {tmp + (size_t)DL1 * HID, tmp + (size_t)DL4 * HID,
                      Wcon + l * 32768, bcon + l * HID, 0.5f, NCON, 256, hb_con};
        GemmJob jc = {tmp + (size_t)DL2 * HID, nullptr,
                      Wcls + l * 16384, bcls2 + l * HID, 1.f, NCLS, 128, hb_cls};
        k_mgemm<<<1563 + 313 + 16, 256, 0, stream>>>(ja, jb, jc, 1563, 313);
    }

    k_score<<<(NOER * 64 + 255) / 256, 256, 0, stream>>>(x_oer, hb, W_cls, s1, s2);
    k_final<<<(ESR + 255) / 256, 256, 0, stream>>>(ei_sr, ei_sr + ESR, s1, s2, b_cls, (float*)d_out);
}

// Round 6
// 533.415 us; speedup vs baseline: 10.8001x; 1.0870x over previous
//
#include <hip/hip_runtime.h>
#include <hip/hip_bf16.h>

#define NOER 100000
#define NCON 20000
#define NCLS 1000
#define FENT 64
#define HID 128
#define ESR 200000
#define EEP 400000
#define ECOV 400000
#define EBEL 100000
#define NEG 0.2f
#define NB_TOT 121000

// packed src-logit offsets (by relation)
#define SL0 0
#define SL1 NOER
#define SL2 (2*NOER)
#define SL3 (2*NOER + NCON)
#define SL4 (2*NOER + 2*NCON)
#define SL_TOT (2*NOER + 2*NCON + NCLS)
// packed dst offsets (dst-logit / CSR segment / tmp row space)
#define DL0 0
#define DL1 NOER
#define DL2 (NOER + NCON)
#define DL3 (NOER + NCON + NCLS)
#define DL4 (2*NOER + NCON + NCLS)
#define DL_TOT (2*NOER + 2*NCON + NCLS)   // 241000
#define EX_TOT 1500000
#define SCAN_B1 ((DL_TOT + 255) / 256)    // 942

typedef unsigned short u16;
typedef unsigned int u32;
typedef short v8s __attribute__((ext_vector_type(8)));
typedef float v4f __attribute__((ext_vector_type(4)));

__device__ __forceinline__ float b2f(u32 bits) { return __uint_as_float(bits << 16); }
__device__ __forceinline__ u16 f2b(float x) {
    __hip_bfloat16 h = __float2bfloat16(x);
    return *(u16*)&h;
}
__device__ __forceinline__ float wredsum(float p) {
#pragma unroll
    for (int off = 32; off; off >>= 1) p += __shfl_down(p, off);
    return p;
}

// ---------------- CSR build ----------------
__device__ __forceinline__ void edge_decode(int e, const int* __restrict__ ep,
                                            const int* __restrict__ cov,
                                            const int* __restrict__ bel,
                                            const int* __restrict__ rcov,
                                            const int* __restrict__ rbel,
                                            int& s, int& g) {
    if (e < 500000) {
        if (e < EEP) { s = ep[e]; g = DL0 + ep[EEP + e]; }
        else { s = e - EEP; g = DL0 + s; }
    } else if (e < 900000)  { int i = e - 500000;  s = cov[i];  g = DL1 + cov[ECOV + i]; }
    else if (e < 1000000)   { int i = e - 900000;  s = bel[i];  g = DL2 + bel[EBEL + i]; }
    else if (e < 1400000)   { int i = e - 1000000; s = rcov[i]; g = DL3 + rcov[ECOV + i]; }
    else                    { int i = e - 1400000; s = rbel[i]; g = DL4 + rbel[EBEL + i]; }
}

__global__ void k_count(const int* __restrict__ ep, const int* __restrict__ cov,
                        const int* __restrict__ bel, const int* __restrict__ rcov,
                        const int* __restrict__ rbel, int* __restrict__ counts) {
    int e = blockIdx.x * blockDim.x + threadIdx.x;
    if (e >= EX_TOT) return;
    int s, g;
    edge_decode(e, ep, cov, bel, rcov, rbel, s, g);
    atomicAdd(counts + g, 1);
}

__global__ void k_scan1(const int* __restrict__ counts, int* __restrict__ part,
                        int* __restrict__ bsum) {
    __shared__ int sm[256];
    int i = blockIdx.x * 256 + threadIdx.x;
    int v = (i < DL_TOT) ? counts[i] : 0;
    sm[threadIdx.x] = v;
    __syncthreads();
#pragma unroll
    for (int off = 1; off < 256; off <<= 1) {
        int x = (threadIdx.x >= off) ? sm[threadIdx.x - off] : 0;
        __syncthreads();
        sm[threadIdx.x] += x;
        __syncthreads();
    }
    if (i < DL_TOT) part[i] = sm[threadIdx.x];
    if (threadIdx.x == 255) bsum[blockIdx.x] = sm[255];
}

__global__ void k_scan2(int* __restrict__ bsum) {
    __shared__ int sm[1024];
    int t = threadIdx.x;
    sm[t] = (t < SCAN_B1) ? bsum[t] : 0;
    __syncthreads();
#pragma unroll
    for (int off = 1; off < 1024; off <<= 1) {
        int x = (t >= off) ? sm[t - off] : 0;
        __syncthreads();
        sm[t] += x;
        __syncthreads();
    }
    if (t < SCAN_B1) bsum[t] = sm[t];
}

__global__ void k_scan3(const int* __restrict__ part, const int* __restrict__ bsum,
                        const int* __restrict__ counts, int* __restrict__ S,
                        int* __restrict__ cursor) {
    int i = blockIdx.x * 256 + threadIdx.x;
    if (i >= DL_TOT) return;
    int b = blockIdx.x;
    int s = part[i] + (b > 0 ? bsum[b - 1] : 0);
    S[i] = s;
    cursor[i] = s - counts[i];
}

__global__ void k_fill(const int* __restrict__ ep, const int* __restrict__ cov,
                       const int* __restrict__ bel, const int* __restrict__ rcov,
                       const int* __restrict__ rbel, int* __restrict__ cursor,
                       int* __restrict__ csr) {
    int e = blockIdx.x * blockDim.x + threadIdx.x;
    if (e >= EX_TOT) return;
    int s, g;
    edge_decode(e, ep, cov, bel, rcov, rbel, s, g);
    int pos = atomicAdd(cursor + g, 1);
    csr[pos] = s;
}

// ---------------- prep: bf16 casts + transposed weight stacks ----------------
__global__ void k_cast(const float* __restrict__ e_oer, const float* __restrict__ e_con,
                       const float* __restrict__ e_cls, u16* __restrict__ eb) {
    int idx = blockIdx.x * blockDim.x + threadIdx.x;
    int i4 = idx * 4;
    if (i4 >= NB_TOT * FENT) return;
    const float* src;
    if (i4 < 6400000) src = e_oer + i4;
    else if (i4 < 7680000) src = e_con + (i4 - 6400000);
    else src = e_cls + (i4 - 7680000);
    float4 v = *(const float4*)src;
    u16* d = eb + i4;
    d[0] = f2b(v.x); d[1] = f2b(v.y); d[2] = f2b(v.z); d[3] = f2b(v.w);
}

// Wt layouts: [cols=128][K] bf16, K-concat of the two relations feeding a dst type
__global__ void k_prep(const float* __restrict__ W_lin, const float* __restrict__ Wsrc,
                       const float* __restrict__ b_gat,
                       u16* __restrict__ Wlt, u16* __restrict__ Woer, u16* __restrict__ Wcon,
                       u16* __restrict__ Wcls, float* __restrict__ boer,
                       float* __restrict__ bcon, float* __restrict__ bcls2) {
    int i = blockIdx.x * 256 + threadIdx.x;
    if (i < 24576) {
        int t = i / 8192, r = i % 8192, c = r >> 6, k = r & 63;
        Wlt[i] = f2b(W_lin[t * 8192 + k * 128 + c]);
        return;
    }
    i -= 24576;
    if (i < 65536) {
        int l = i >> 15, r = i & 32767, c = r >> 8, k2 = r & 255;
        int rel = 5 * l + (k2 < 128 ? 0 : 3), k = k2 & 127;
        Woer[i] = f2b(Wsrc[(size_t)rel * 16384 + k * 128 + c]);
        return;
    }
    i -= 65536;
    if (i < 65536) {
        int l = i >> 15, r = i & 32767, c = r >> 8, k2 = r & 255;
        int rel = 5 * l + (k2 < 128 ? 1 : 4), k = k2 & 127;
        Wcon[i] = f2b(Wsrc[(size_t)rel * 16384 + k * 128 + c]);
        return;
    }
    i -= 65536;
    if (i < 32768) {
        int l = i >> 14, r = i & 16383, c = r >> 7, k = r & 127;
        Wcls[i] = f2b(Wsrc[(size_t)(5 * l + 2) * 16384 + k * 128 + c]);
        return;
    }
    i -= 32768;
    if (i < 256) { int l = i >> 7, c = i & 127;
        boer[i] = 0.5f * (b_gat[(5 * l + 0) * 128 + c] + b_gat[(5 * l + 3) * 128 + c]); return; }
    i -= 256;
    if (i < 256) { int l = i >> 7, c = i & 127;
        bcon[i] = 0.5f * (b_gat[(5 * l + 1) * 128 + c] + b_gat[(5 * l + 4) * 128 + c]); return; }
    i -= 256;
    if (i < 256) { int l = i >> 7, c = i & 127;
        bcls2[i] = b_gat[(5 * l + 2) * 128 + c]; }
}

// all 20 attention projection vectors (f32 weights)
__global__ void k_wvec(const float* __restrict__ Wsrc, const float* __restrict__ as_,
                       const float* __restrict__ Wdst, const float* __restrict__ ad,
                       float* __restrict__ wsv, float* __restrict__ wdv) {
    int a = blockIdx.x >> 5;
    int r = ((blockIdx.x & 31) << 2) + (threadIdx.x >> 6);
    int lane = threadIdx.x & 63;
    const float *W, *v;
    float* o;
    if (a < 10) { W = Wsrc + (size_t)a * HID * HID; v = as_ + a * HID; o = wsv + a * HID; }
    else { W = Wdst + (size_t)(a - 10) * HID * HID; v = ad + (a - 10) * HID; o = wdv + (a - 10) * HID; }
    float p = W[r * HID + lane] * v[lane] + W[r * HID + 64 + lane] * v[64 + lane];
    p = wredsum(p);
    if (lane == 0) o[r] = p;
}

// ---------------- MFMA GEMM: out[r,0:128] = bf16(scale * (A @ Wt^T) + bias) ----------------
struct GemmJob {
    const u16* A0;
    const u16* A1;
    const u16* Wt;
    const float* bias;
    float scale;
    int n, K;
    u16* out;
};

__global__ __launch_bounds__(256) void k_mgemm(GemmJob j0, GemmJob j1, GemmJob j2,
                                               int nb0, int nb1) {
    __shared__ u16 lA[64][40];
    __shared__ u16 lB[128][40];
    GemmJob J;
    int b = blockIdx.x;
    if (b < nb0) J = j0;
    else if (b < nb0 + nb1) { J = j1; b -= nb0; }
    else { J = j2; b -= nb0 + nb1; }
    const int row0 = b * 64;
    const int tid = threadIdx.x, lane = tid & 63, w = tid >> 6;
    const int wr = w >> 1, wc = w & 1;
    const int fr = lane & 15, kg = lane >> 4;
    const int astride = J.A1 ? 128 : J.K;
    v4f acc[2][4];
#pragma unroll
    for (int i = 0; i < 2; ++i)
#pragma unroll
        for (int c = 0; c < 4; ++c) acc[i][c] = (v4f){0.f, 0.f, 0.f, 0.f};

    for (int k0 = 0; k0 < J.K; k0 += 32) {
        const u16* Asrc; int kk;
        if (k0 < 128) { Asrc = J.A0; kk = k0; } else { Asrc = J.A1; kk = k0 - 128; }
        __syncthreads();
        {
            int r = tid >> 2, seg = tid & 3;
            int gr = row0 + r;
            uint4 u = make_uint4(0u, 0u, 0u, 0u);
            if (gr < J.n) u = *(const uint4*)(Asrc + (size_t)gr * astride + kk + seg * 8);
            *(uint4*)&lA[r][seg * 8] = u;
        }
#pragma unroll
        for (int i = 0; i < 2; ++i) {
            int m = tid * 2 + i, c = m >> 2, seg = m & 3;
            uint4 u = *(const uint4*)(J.Wt + (size_t)c * J.K + k0 + seg * 8);
            *(uint4*)&lB[c][seg * 8] = u;
        }
        __syncthreads();
        v8s a0 = *(const v8s*)&lA[32 * wr + fr][8 * kg];
        v8s a1 = *(const v8s*)&lA[32 * wr + 16 + fr][8 * kg];
#pragma unroll
        for (int c = 0; c < 4; ++c) {
            v8s bf = *(const v8s*)&lB[64 * wc + 16 * c + fr][8 * kg];
            acc[0][c] = __builtin_amdgcn_mfma_f32_16x16x32_bf16(a0, bf, acc[0][c], 0, 0, 0);
            acc[1][c] = __builtin_amdgcn_mfma_f32_16x16x32_bf16(a1, bf, acc[1][c], 0, 0, 0);
        }
    }
#pragma unroll
    for (int i = 0; i < 2; ++i)
#pragma unroll
        for (int c = 0; c < 4; ++c) {
            int col = 64 * wc + 16 * c + fr;
            float bv = J.bias[col];
#pragma unroll
            for (int jj = 0; jj < 4; ++jj) {
                int gr = row0 + 32 * wr + 16 * i + 4 * kg + jj;
                if (gr < J.n) J.out[(size_t)gr * 128 + col] = f2b(acc[i][c][jj] * J.scale + bv);
            }
        }
}

// ---------------- per-node logit dots ----------------
__global__ void k_dots_all(const u16* __restrict__ hb, const float* __restrict__ wsv,
                           const float* __restrict__ wdv, float* __restrict__ slp,
                           float* __restrict__ dlp, int lb) {
    int t = blockIdx.x * blockDim.x + threadIdx.x;
    int n = t >> 6, lane = t & 63;
    if (n >= NB_TOT) return;
    const u32* h;
    int m;
    const float *v0, *v1, *v2, *v3;
    float *o0, *o1, *o2, *o3;
    if (n < NOER) {
        m = n; h = (const u32*)hb;
        v0 = wsv + (lb + 0) * HID; o0 = slp + SL0 + m;
        v1 = wsv + (lb + 1) * HID; o1 = slp + SL1 + m;
        v2 = wdv + (lb + 0) * HID; o2 = dlp + DL0 + m;
        v3 = wdv + (lb + 3) * HID; o3 = dlp + DL3 + m;
    } else if (n < NOER + NCON) {
        m = n - NOER; h = (const u32*)(hb + (size_t)NOER * HID);
        v0 = wsv + (lb + 2) * HID; o0 = slp + SL2 + m;
        v1 = wsv + (lb + 3) * HID; o1 = slp + SL3 + m;
        v2 = wdv + (lb + 1) * HID; o2 = dlp + DL1 + m;
        v3 = wdv + (lb + 4) * HID; o3 = dlp + DL4 + m;
    } else {
        m = n - NOER - NCON; h = (const u32*)(hb + (size_t)(NOER + NCON) * HID);
        v0 = wsv + (lb + 4) * HID; o0 = slp + SL4 + m;
        v1 = wdv + (lb + 2) * HID; o1 = dlp + DL2 + m;
        v2 = nullptr; o2 = nullptr; v3 = nullptr; o3 = nullptr;
    }
    u32 hu = h[(size_t)m * 64 + lane];
    float h0 = b2f(hu & 0xffffu), h1 = b2f(hu >> 16);
    float p0 = 0.f, p1 = 0.f, p2 = 0.f, p3 = 0.f;
    { float2 a = *(const float2*)(v0 + 2 * lane); p0 = h0 * a.x + h1 * a.y; }
    { float2 a = *(const float2*)(v1 + 2 * lane); p1 = h0 * a.x + h1 * a.y; }
    if (v2) { float2 a = *(const float2*)(v2 + 2 * lane); p2 = h0 * a.x + h1 * a.y; }
    if (v3) { float2 a = *(const float2*)(v3 + 2 * lane); p3 = h0 * a.x + h1 * a.y; }
    p0 = wredsum(p0); p1 = wredsum(p1); p2 = wredsum(p2); p3 = wredsum(p3);
    if (lane == 0) {
        o0[0] = p0; o1[0] = p1;
        if (o2) o2[0] = p2;
        if (o3) o3[0] = p3;
    }
}

// ---------------- fused GAT aggregation: 4 edges x 16 channel-lanes per wave ----------------
// One wave per dst. Lane L: edge-slot sub=L>>4, channels (L&15)*8 via one dwordx4 gather.
// Prefetch: lane j computes ex_j for chunk edge j (lane-parallel); den accumulated there.
// Inner loop: 4 edges per iteration, 16B gathers, independent across iterations.
__global__ __launch_bounds__(256) void k_agg_all(const int* __restrict__ csr,
                                                 const int* __restrict__ S,
                                                 const float* __restrict__ slp,
                                                 const float* __restrict__ dlp,
                                                 const u16* __restrict__ hb,
                                                 u16* __restrict__ tmp) {
    int g = blockIdx.x * 4 + (threadIdx.x >> 6);
    if (g >= DL_TOT) return;
    int lane = threadIdx.x & 63;
    int sub = lane >> 4;          // edge slot 0..3
    int c4 = (lane & 15) * 4;     // u32 index within 64-u32 row (8 bf16 channels)
    const u32* h;
    int sb;
    if (g < DL1)      { h = (const u32*)hb; sb = SL0; }
    else if (g < DL2) { h = (const u32*)hb; sb = SL1; }
    else if (g < DL3) { h = (const u32*)(hb + (size_t)NOER * HID); sb = SL2; }
    else if (g < DL4) { h = (const u32*)(hb + (size_t)NOER * HID); sb = SL3; }
    else              { h = (const u32*)(hb + (size_t)(NOER + NCON) * HID); sb = SL4; }
    int beg = (g == 0) ? 0 : S[g - 1];
    int end = S[g];
    float dlv = dlp[g];
    float acc[8] = {};
    float denp = 0.f;
    for (int c0 = beg; c0 < end; c0 += 64) {
        int nchunk = end - c0;
        if (nchunk > 64) nchunk = 64;
        int s_l = 0;
        float ex_l = 0.f;
        if (lane < nchunk) {
            s_l = csr[c0 + lane];
            float lg = slp[sb + s_l] + dlv;
            lg = lg > 0.f ? lg : NEG * lg;
            ex_l = expf(lg);
            denp += ex_l;
        }
#pragma unroll 2
        for (int j0 = 0; j0 < nchunk; j0 += 4) {
            int j = j0 + sub;                  // may exceed nchunk on tail: ex=0 there
            int s = __shfl(s_l, j);
            float ex = __shfl(ex_l, j);
            uint4 hu = *(const uint4*)(h + (size_t)s * 64 + c4);
#pragma unroll
            for (int q = 0; q < 4; ++q) {
                u32 w = ((const u32*)&hu)[q];
                acc[2 * q]     = fmaf(ex, b2f(w & 0xffffu), acc[2 * q]);
                acc[2 * q + 1] = fmaf(ex, b2f(w >> 16), acc[2 * q + 1]);
            }
        }
    }
    // reduce the 4 edge-slots (lanes L, L+16, L+32, L+48 share channels)
#pragma unroll
    for (int q = 0; q < 8; ++q) {
        acc[q] += __shfl_down(acc[q], 32);
        acc[q] += __shfl_down(acc[q], 16);
    }
    // den: butterfly so lanes 0-15 have the full sum
    float den = denp;
#pragma unroll
    for (int off = 32; off; off >>= 1) den += __shfl_xor(den, off);
    if (sub == 0) {
        float inv = (end > beg) ? 1.f / den : 0.f;
        uint4 r;
        r.x = (u32)f2b(acc[0] * inv) | ((u32)f2b(acc[1] * inv) << 16);
        r.y = (u32)f2b(acc[2] * inv) | ((u32)f2b(acc[3] * inv) << 16);
        r.z = (u32)f2b(acc[4] * inv) | ((u32)f2b(acc[5] * inv) << 16);
        r.w = (u32)f2b(acc[6] * inv) | ((u32)f2b(acc[7] * inv) << 16);
        *(uint4*)((u32*)tmp + (size_t)g * 64 + c4) = r;
    }
}

// ---------------- classifier ----------------
__global__ void k_score(const float* __restrict__ x, const u16* __restrict__ hb,
                        const float* __restrict__ Wc, float* __restrict__ s1,
                        float* __restrict__ s2) {
    int t = blockIdx.x * blockDim.x + threadIdx.x;
    int n = t >> 6, lane = t & 63;
    if (n >= NOER) return;
    float xv = x[(size_t)n * FENT + lane];
    u32 hu = ((const u32*)hb)[(size_t)n * 64 + lane];
    float h0 = b2f(hu & 0xffffu), h1 = b2f(hu >> 16);
    float2 wa = *(const float2*)(Wc + 64 + 2 * lane);
    float2 wb = *(const float2*)(Wc + 256 + 2 * lane);
    float p1 = xv * Wc[lane] + h0 * wa.x + h1 * wa.y;
    float p2 = xv * Wc[192 + lane] + h0 * wb.x + h1 * wb.y;
#pragma unroll
    for (int off = 32; off; off >>= 1) { p1 += __shfl_down(p1, off); p2 += __shfl_down(p2, off); }
    if (lane == 0) { s1[n] = p1; s2[n] = p2; }
}

__global__ void k_final(const int* __restrict__ src, const int* __restrict__ dst,
                        const float* __restrict__ s1, const float* __restrict__ s2,
                        const float* __restrict__ bcls, float* __restrict__ out) {
    int e = blockIdx.x * blockDim.x + threadIdx.x;
    if (e >= ESR) return;
    out[e] = s1[src[e]] + s2[dst[e]] + bcls[0];
}

extern "C" void kernel_launch(void* const* d_in, const int* in_sizes, int n_in,
                              void* d_out, int out_size, void* d_ws, size_t ws_size,
                              hipStream_t stream) {
    const float* x_oer   = (const float*)d_in[0];
    const float* e_oer   = (const float*)d_in[3];
    const float* e_con   = (const float*)d_in[4];
    const float* e_cls   = (const float*)d_in[5];
    const float* W_lin   = (const float*)d_in[6];
    const float* b_lin   = (const float*)d_in[7];
    const float* Wsrc    = (const float*)d_in[8];
    const float* Wdst    = (const float*)d_in[9];
    const float* att_src = (const float*)d_in[10];
    const float* att_dst = (const float*)d_in[11];
    const float* b_gat   = (const float*)d_in[12];
    const float* W_cls   = (const float*)d_in[13];
    const float* b_cls   = (const float*)d_in[14];
    const int* ei_sr   = (const int*)d_in[15];
    const int* ei_cov  = (const int*)d_in[16];
    const int* ei_bel  = (const int*)d_in[17];
    const int* ei_rcov = (const int*)d_in[18];
    const int* ei_rbel = (const int*)d_in[19];
    const int* ei_ep   = (const int*)d_in[20];

    float* ws = (float*)d_ws;
    size_t o = 0;
    u16* hb  = (u16*)(ws + o); o += (size_t)NB_TOT * HID / 2;
    u16* eb  = (u16*)(ws + o); o += (size_t)NB_TOT * FENT / 2;
    u16* tmp = (u16*)(ws + o); o += (size_t)DL_TOT * HID / 2;
    float* slp  = ws + o; o += SL_TOT;
    float* dlp  = ws + o; o += DL_TOT;
    float* wsv  = ws + o; o += 10 * HID;
    float* wdv  = ws + o; o += 10 * HID;
    u16* Wlt  = (u16*)(ws + o); o += 3 * HID * FENT / 2;
    u16* Woer = (u16*)(ws + o); o += 2 * HID * 256 / 2;
    u16* Wcon = (u16*)(ws + o); o += 2 * HID * 256 / 2;
    u16* Wcls = (u16*)(ws + o); o += 2 * HID * HID / 2;
    float* boer  = ws + o; o += 2 * HID;
    float* bcon  = ws + o; o += 2 * HID;
    float* bcls2 = ws + o; o += 2 * HID;
    float* s1 = ws + o; o += NOER;
    float* s2 = ws + o; o += NOER;
    int* counts = (int*)(ws + o); o += DL_TOT;
    int* part   = (int*)(ws + o); o += DL_TOT;
    int* S      = (int*)(ws + o); o += DL_TOT;
    int* cursor = (int*)(ws + o); o += DL_TOT;
    int* bsum   = (int*)(ws + o); o += 1024;
    int* csr    = (int*)(ws + o); o += EX_TOT;

    u16* hb_con = hb + (size_t)NOER * HID;
    u16* hb_cls = hb + (size_t)(NOER + NCON) * HID;

    // ---- CSR build ----
    hipMemsetAsync(counts, 0, DL_TOT * sizeof(int), stream);
    k_count<<<(EX_TOT + 255) / 256, 256, 0, stream>>>(ei_ep, ei_cov, ei_bel, ei_rcov, ei_rbel, counts);
    k_scan1<<<SCAN_B1, 256, 0, stream>>>(counts, part, bsum);
    k_scan2<<<1, 1024, 0, stream>>>(bsum);
    k_scan3<<<SCAN_B1, 256, 0, stream>>>(part, bsum, counts, S, cursor);
    k_fill<<<(EX_TOT + 255) / 256, 256, 0, stream>>>(ei_ep, ei_cov, ei_bel, ei_rcov, ei_rbel, cursor, csr);

    // ---- prep ----
    k_prep<<<739, 256, 0, stream>>>(W_lin, Wsrc, b_gat, Wlt, Woer, Wcon, Wcls, boer, bcon, bcls2);
    k_cast<<<(NB_TOT * FENT / 4 + 255) / 256, 256, 0, stream>>>(e_oer, e_con, e_cls, eb);
    k_wvec<<<640, 256, 0, stream>>>(Wsrc, att_src, Wdst, att_dst, wsv, wdv);

    // ---- input projections ----
    {
        GemmJob ja = {eb, nullptr, Wlt, b_lin, 1.f, NOER, FENT, hb};
        GemmJob jb = {eb + (size_t)NOER * FENT, nullptr, Wlt + 8192, b_lin + 128, 1.f, NCON, FENT, hb_con};
        GemmJob jc = {eb + (size_t)(NOER + NCON) * FENT, nullptr, Wlt + 16384, b_lin + 256, 1.f, NCLS, FENT, hb_cls};
        k_mgemm<<<1563 + 313 + 16, 256, 0, stream>>>(ja, jb, jc, 1563, 313);
    }

    for (int l = 0; l < 2; ++l) {
        int lb = l * 5;
        k_dots_all<<<NB_TOT * 64 / 256, 256, 0, stream>>>(hb, wsv, wdv, slp, dlp, lb);
        k_agg_all<<<DL_TOT / 4, 256, 0, stream>>>(csr, S, slp, dlp, hb, tmp);
        GemmJob ja = {tmp + (size_t)DL0 * HID, tmp + (size_t)DL3 * HID,
                      Woer + l * 32768, boer + l * HID, 0.5f, NOER, 256, hb};
        GemmJob jb = {tmp + (size_t)DL1 * HID, tmp + (size_t)DL4 * HID,
                      Wcon + l * 32768, bcon + l * HID, 0.5f, NCON, 256, hb_con};
        GemmJob jc = {tmp + (size_t)DL2 * HID, nullptr,
                      Wcls + l * 16384, bcls2 + l * HID, 1.f, NCLS, 128, hb_cls};
        k_mgemm<<<1563 + 313 + 16, 256, 0, stream>>>(ja, jb, jc, 1563, 313);
    }

    k_score<<<(NOER * 64 + 255) / 256, 256, 0, stream>>>(x_oer, hb, W_cls, s1, s2);
    k_final<<<(ESR + 255) / 256, 256, 0, stream>>>(ei_sr, ei_sr + ESR, s1, s2, b_cls, (float*)d_out);
}